// Round 1
// baseline (618.073 us; speedup 1.0000x reference)
//
#include <hip/hip_runtime.h>

// PerceiverAttention fused pipeline, bf16 MFMA path.
// b=8 n=4096 m=64 dim=1024 H=16 DH=64 inner=1024

using u16 = unsigned short;
typedef short bf16x8_t __attribute__((ext_vector_type(8)));
typedef float f32x4_t __attribute__((ext_vector_type(4)));

__device__ __forceinline__ u16 f2bf(float f) {
    union { float f; unsigned u; } v; v.f = f;
    unsigned r = v.u + 0x7fffu + ((v.u >> 16) & 1u);   // RNE
    return (u16)(r >> 16);
}

template <typename T> __device__ __forceinline__ T cvt_out(float v);
template <> __device__ __forceinline__ float cvt_out<float>(float v) { return v; }
template <> __device__ __forceinline__ u16   cvt_out<u16>(float v)   { return f2bf(v); }

// async global->LDS, 16B per lane; lds ptr must be wave-uniform (HW adds lane*16)
__device__ __forceinline__ void cp16(const void* g, void* l) {
    __builtin_amdgcn_global_load_lds((const __attribute__((address_space(1))) unsigned int*)g,
                                     (__attribute__((address_space(3))) unsigned int*)l, 16, 0, 0);
}

// ---------------- fp32 -> bf16 convert (with optional scale) ----------------
__global__ void cvt_bf16(const float* __restrict__ src, u16* __restrict__ dst,
                         int n4, float scale) {
    int i = blockIdx.x * 256 + threadIdx.x;
    if (i >= n4) return;
    float4 v = ((const float4*)src)[i];
    ushort4 o;
    o.x = f2bf(v.x * scale); o.y = f2bf(v.y * scale);
    o.z = f2bf(v.z * scale); o.w = f2bf(v.w * scale);
    ((ushort4*)dst)[i] = o;
}

// ---------------- C[M,N] = A[M,K] * B[N,K]^T, bf16 in, fp32 acc ----------------
// m97 structure: 128x128 tile, BK=64, 4 waves each 64x64, global_load_lds x16.
template <typename OutT>
__global__ __launch_bounds__(256) void gemm_bt(const u16* __restrict__ A,
                                               const u16* __restrict__ B,
                                               OutT* __restrict__ C,
                                               int M, int N, int K) {
    __shared__ __align__(16) u16 As[128 * 64];
    __shared__ __align__(16) u16 Bs[128 * 64];
    const int tid = threadIdx.x;
    const int wid = tid >> 6, lane = tid & 63;
    const int bm = blockIdx.y * 128, bn = blockIdx.x * 128;
    const int srow = lane >> 3, scol = (lane & 7) * 8;
    const int frow = lane & 15, fk = (lane >> 4) * 8;
    const int wr = (wid >> 1) * 64, wc = (wid & 1) * 64;

    f32x4_t acc[4][4];
#pragma unroll
    for (int i = 0; i < 4; ++i)
#pragma unroll
        for (int j = 0; j < 4; ++j) acc[i][j] = (f32x4_t){0.f, 0.f, 0.f, 0.f};

    for (int k0 = 0; k0 < K; k0 += 64) {
#pragma unroll
        for (int t = 0; t < 4; ++t) {
            const int c = wid * 4 + t;
            const int r = c * 8 + srow;
            cp16(A + (size_t)(bm + r) * K + k0 + scol, As + c * 512);
            cp16(B + (size_t)(bn + r) * K + k0 + scol, Bs + c * 512);
        }
        __syncthreads();
#pragma unroll
        for (int ks = 0; ks < 2; ++ks) {
            bf16x8_t af[4], bfv[4];
#pragma unroll
            for (int i = 0; i < 4; ++i) {
                af[i]  = *(const bf16x8_t*)(As + (wr + i * 16 + frow) * 64 + ks * 32 + fk);
                bfv[i] = *(const bf16x8_t*)(Bs + (wc + i * 16 + frow) * 64 + ks * 32 + fk);
            }
#pragma unroll
            for (int i = 0; i < 4; ++i)
#pragma unroll
                for (int j = 0; j < 4; ++j)
                    acc[i][j] = __builtin_amdgcn_mfma_f32_16x16x32_bf16(af[i], bfv[j], acc[i][j], 0, 0, 0);
        }
        __syncthreads();
    }
    // C/D layout: col = lane&15, row = (lane>>4)*4 + reg
    const int cr = (lane >> 4) * 4, cc = lane & 15;
#pragma unroll
    for (int i = 0; i < 4; ++i)
#pragma unroll
        for (int j = 0; j < 4; ++j) {
            size_t base = (size_t)(bm + wr + i * 16 + cr) * N + (bn + wc + j * 16 + cc);
#pragma unroll
            for (int r = 0; r < 4; ++r)
                C[base + (size_t)r * N] = cvt_out<OutT>(acc[i][j][r]);
        }
}

// ---------------- attention + variance loss, one block per (b,h) ----------------
// q: (512,1024) bf16 pre-scaled. kv: (32768,2048) bf16, k = cols[0,1024), v = +1024.
// ao: (512,1024) bf16 out (b*64+m, h*64+d). loss: scalar fp32 (pre-zeroed).
__global__ __launch_bounds__(256, 1) void attn_k(const u16* __restrict__ q,
                                                 const u16* __restrict__ kv,
                                                 const int* __restrict__ mask,
                                                 u16* __restrict__ ao,
                                                 float* __restrict__ loss) {
    const int bh = blockIdx.x, b = bh >> 4, h = bh & 15;
    const int tid = threadIdx.x, wid = tid >> 6, lane = tid & 63;
    const int frow = lane & 15, fk = (lane >> 4) * 8, cr = (lane >> 4) * 4;

    __shared__ __align__(16) u16 qs[64 * 64];       // q tile
    __shared__ __align__(16) u16 ks[256 * 64];      // k chunk; reused as P (64x256) and as Os (fp32 64x64)
    __shared__ __align__(16) u16 vt[64 * 256];      // v^T chunk: vt[d][j]
    __shared__ float maskf[256];
    __shared__ float Mpart[4][64];
    __shared__ float Mrow[64];
    __shared__ float Rpart[4][64];
    __shared__ float Rfinal[64];
    __shared__ float lossP[4];

    const size_t kvbase = (size_t)b * 4096 * 2048 + (size_t)h * 64;

    // stage q tile (async; drained by first in-loop barrier)
#pragma unroll
    for (int t = 0; t < 2; ++t) {
        int c = wid * 2 + t;
        int r = c * 8 + (lane >> 3);
        cp16(q + (size_t)(b * 64 + r) * 1024 + h * 64 + (lane & 7) * 8, qs + c * 512);
    }

    // ---------- phase 1: row maxes over unmasked columns ----------
    float mloc[16];
#pragma unroll
    for (int i = 0; i < 16; ++i) mloc[i] = -3.0e38f;

    for (int ch = 0; ch < 16; ++ch) {
        const int j0 = ch * 256;
        __syncthreads();
#pragma unroll
        for (int t = 0; t < 8; ++t) {
            int c = wid * 8 + t;
            int r = c * 8 + (lane >> 3);
            cp16(kv + kvbase + (size_t)(j0 + r) * 2048 + (lane & 7) * 8, ks + c * 512);
        }
        maskf[tid] = (mask[b * 4096 + j0 + tid] != 0) ? 1.f : 0.f;
        __syncthreads();

        f32x4_t sacc[4][4];
#pragma unroll
        for (int i = 0; i < 4; ++i)
#pragma unroll
            for (int j = 0; j < 4; ++j) sacc[i][j] = (f32x4_t){0.f, 0.f, 0.f, 0.f};
#pragma unroll
        for (int ks2 = 0; ks2 < 2; ++ks2) {
            bf16x8_t af[4], bfv[4];
#pragma unroll
            for (int i = 0; i < 4; ++i) {
                af[i]  = *(const bf16x8_t*)(qs + (i * 16 + frow) * 64 + ks2 * 32 + fk);
                bfv[i] = *(const bf16x8_t*)(ks + (wid * 64 + i * 16 + frow) * 64 + ks2 * 32 + fk);
            }
#pragma unroll
            for (int i = 0; i < 4; ++i)
#pragma unroll
                for (int j = 0; j < 4; ++j)
                    sacc[i][j] = __builtin_amdgcn_mfma_f32_16x16x32_bf16(af[i], bfv[j], sacc[i][j], 0, 0, 0);
        }
#pragma unroll
        for (int nt = 0; nt < 4; ++nt) {
            const int jl = wid * 64 + nt * 16 + frow;
            if (maskf[jl] < 0.5f) {
#pragma unroll
                for (int mt = 0; mt < 4; ++mt)
#pragma unroll
                    for (int r = 0; r < 4; ++r)
                        mloc[mt * 4 + r] = fmaxf(mloc[mt * 4 + r], sacc[mt][nt][r]);
            }
        }
    }
#pragma unroll
    for (int i = 0; i < 16; ++i) {
        float v = mloc[i];
        v = fmaxf(v, __shfl_xor(v, 1)); v = fmaxf(v, __shfl_xor(v, 2));
        v = fmaxf(v, __shfl_xor(v, 4)); v = fmaxf(v, __shfl_xor(v, 8));
        mloc[i] = v;
    }
    if ((lane & 15) == 0) {
#pragma unroll
        for (int mt = 0; mt < 4; ++mt)
#pragma unroll
            for (int r = 0; r < 4; ++r)
                Mpart[wid][mt * 16 + cr + r] = mloc[mt * 4 + r];
    }
    __syncthreads();
    if (tid < 64)
        Mrow[tid] = fmaxf(fmaxf(Mpart[0][tid], Mpart[1][tid]),
                          fmaxf(Mpart[2][tid], Mpart[3][tid]));
    __syncthreads();

    // ---------- phase 2: softmax + variance stats + P@V ----------
    f32x4_t oacc[4][4];
#pragma unroll
    for (int i = 0; i < 4; ++i)
#pragma unroll
        for (int j = 0; j < 4; ++j) oacc[i][j] = (f32x4_t){0.f, 0.f, 0.f, 0.f};
    float rloc[16];
#pragma unroll
    for (int i = 0; i < 16; ++i) rloc[i] = 0.f;
    float lossacc = 0.f;

    for (int ch = 0; ch < 16; ++ch) {
        const int j0 = ch * 256;
        __syncthreads();                       // prev chunk fully consumed
#pragma unroll
        for (int t = 0; t < 8; ++t) {
            int c = wid * 8 + t;
            int r = c * 8 + (lane >> 3);
            cp16(kv + kvbase + (size_t)(j0 + r) * 2048 + (lane & 7) * 8, ks + c * 512);
        }
        {   // stage v transposed: vt[d][j_local]
            const u16* vrow = kv + kvbase + 1024 + (size_t)(j0 + tid) * 2048;
#pragma unroll
            for (int p = 0; p < 8; ++p) {
                bf16x8_t v = *(const bf16x8_t*)(vrow + p * 8);
#pragma unroll
                for (int e = 0; e < 8; ++e) vt[(p * 8 + e) * 256 + tid] = (u16)v[e];
            }
        }
        maskf[tid] = (mask[b * 4096 + j0 + tid] != 0) ? 1.f : 0.f;
        __syncthreads();

        f32x4_t sacc[4][4];
#pragma unroll
        for (int i = 0; i < 4; ++i)
#pragma unroll
            for (int j = 0; j < 4; ++j) sacc[i][j] = (f32x4_t){0.f, 0.f, 0.f, 0.f};
#pragma unroll
        for (int ks2 = 0; ks2 < 2; ++ks2) {
            bf16x8_t af[4], bfv[4];
#pragma unroll
            for (int i = 0; i < 4; ++i) {
                af[i]  = *(const bf16x8_t*)(qs + (i * 16 + frow) * 64 + ks2 * 32 + fk);
                bfv[i] = *(const bf16x8_t*)(ks + (wid * 64 + i * 16 + frow) * 64 + ks2 * 32 + fk);
            }
#pragma unroll
            for (int i = 0; i < 4; ++i)
#pragma unroll
                for (int j = 0; j < 4; ++j)
                    sacc[i][j] = __builtin_amdgcn_mfma_f32_16x16x32_bf16(af[i], bfv[j], sacc[i][j], 0, 0, 0);
        }
        __syncthreads();                       // all k reads done before P overwrites ks

        // P (bf16) into ks as [m][256]; stats per column
#pragma unroll
        for (int nt = 0; nt < 4; ++nt) {
            const int jl = wid * 64 + nt * 16 + frow;
            const bool msk = maskf[jl] > 0.5f;
            float c1 = 0.f, c2 = 0.f;
#pragma unroll
            for (int mt = 0; mt < 4; ++mt) {
#pragma unroll
                for (int r = 0; r < 4; ++r) {
                    const int row = mt * 16 + cr + r;
                    const float t = sacc[mt][nt][r] - Mrow[row];
                    const float p = msk ? 0.f : __expf(t);
                    rloc[mt * 4 + r] += p;
                    c1 += msk ? 0.f : t;
                    c2 += msk ? 0.f : t * t;
                    ks[row * 256 + jl] = f2bf(p);
                }
            }
            c1 += __shfl_xor(c1, 16); c1 += __shfl_xor(c1, 32);
            c2 += __shfl_xor(c2, 16); c2 += __shfl_xor(c2, 32);
            if (lane < 16 && !msk) {
                const float var = (c2 - c1 * c1 * (1.f / 64.f)) * (1.f / 63.f);
                lossacc += fmaxf(1.f - sqrtf(var + 1e-4f), 0.f);
            }
        }
        // P@V over this wave's own k-slice (same-wave LDS data, no barrier needed)
#pragma unroll
        for (int ks2 = 0; ks2 < 2; ++ks2) {
            bf16x8_t pa[4], vb[4];
#pragma unroll
            for (int i = 0; i < 4; ++i) {
                pa[i] = *(const bf16x8_t*)(ks + (i * 16 + frow) * 256 + wid * 64 + ks2 * 32 + fk);
                vb[i] = *(const bf16x8_t*)(vt + (i * 16 + frow) * 256 + wid * 64 + ks2 * 32 + fk);
            }
#pragma unroll
            for (int i = 0; i < 4; ++i)
#pragma unroll
                for (int j = 0; j < 4; ++j)
                    oacc[i][j] = __builtin_amdgcn_mfma_f32_16x16x32_bf16(pa[i], vb[j], oacc[i][j], 0, 0, 0);
        }
    }

    // ---------- combine waves, normalize, write ----------
    __syncthreads();
    float* Os = (float*)ks;
    for (int i = tid; i < 4096; i += 256) Os[i] = 0.f;
#pragma unroll
    for (int i = 0; i < 16; ++i) {
        float v = rloc[i];
        v += __shfl_xor(v, 1); v += __shfl_xor(v, 2);
        v += __shfl_xor(v, 4); v += __shfl_xor(v, 8);
        rloc[i] = v;
    }
    if ((lane & 15) == 0) {
#pragma unroll
        for (int mt = 0; mt < 4; ++mt)
#pragma unroll
            for (int r = 0; r < 4; ++r)
                Rpart[wid][mt * 16 + cr + r] = rloc[mt * 4 + r];
    }
    __syncthreads();
#pragma unroll
    for (int mt = 0; mt < 4; ++mt)
#pragma unroll
        for (int dt = 0; dt < 4; ++dt)
#pragma unroll
            for (int r = 0; r < 4; ++r)
                atomicAdd(&Os[(mt * 16 + cr + r) * 64 + dt * 16 + frow], oacc[mt][dt][r]);
    if (tid < 64) Rfinal[tid] = Rpart[0][tid] + Rpart[1][tid] + Rpart[2][tid] + Rpart[3][tid];
    __syncthreads();
    for (int e = tid; e < 4096; e += 256) {
        const int row = e >> 6, d = e & 63;
        ao[(size_t)(b * 64 + row) * 1024 + h * 64 + d] = f2bf(Os[e] / Rfinal[row]);
    }
    float v = lossacc;
    v += __shfl_xor(v, 1); v += __shfl_xor(v, 2); v += __shfl_xor(v, 4);
    v += __shfl_xor(v, 8); v += __shfl_xor(v, 16); v += __shfl_xor(v, 32);
    if (lane == 0) lossP[wid] = v;
    __syncthreads();
    if (tid == 0)
        atomicAdd(loss, (lossP[0] + lossP[1] + lossP[2] + lossP[3]) * (1.f / 524288.f));
}

// ---------------- host ----------------
extern "C" void kernel_launch(void* const* d_in, const int* in_sizes, int n_in,
                              void* d_out, int out_size, void* d_ws, size_t ws_size,
                              hipStream_t stream) {
    const float* x    = (const float*)d_in[0];
    const float* lat  = (const float*)d_in[1];
    const int*   mask = (const int*)d_in[2];
    const float* Wq   = (const float*)d_in[3];
    const float* Wkv  = (const float*)d_in[4];
    const float* Wout = (const float*)d_in[5];
    float* out = (float*)d_out;

    char* ws = (char*)d_ws;
    u16* x_bf    = (u16*)(ws);                    // 67,108,864 B
    u16* kvb     = (u16*)(ws + 67108864);         // 134,217,728 B
    u16* wq_bf   = (u16*)(ws + 201326592);        // 2 MB
    u16* wkv_bf  = (u16*)(ws + 203423744);        // 4 MB
    u16* wout_bf = (u16*)(ws + 207618048);        // 2 MB
    u16* lat_bf  = (u16*)(ws + 209715200);        // 1 MB
    u16* q_bf    = (u16*)(ws + 210763776);        // 1 MB
    u16* ao_bf   = (u16*)(ws + 211812352);        // 1 MB

    hipMemsetAsync(out + 524288, 0, 4, stream);   // zero loss accumulator

    cvt_bf16<<<32768, 256, 0, stream>>>(x, x_bf, 8388608, 1.f);
    cvt_bf16<<<512, 256, 0, stream>>>(lat, lat_bf, 131072, 1.f);
    cvt_bf16<<<1024, 256, 0, stream>>>(Wq, wq_bf, 262144, 0.125f);  // fold dh^-0.5
    cvt_bf16<<<2048, 256, 0, stream>>>(Wkv, wkv_bf, 524288, 1.f);
    cvt_bf16<<<1024, 256, 0, stream>>>(Wout, wout_bf, 262144, 1.f);

    dim3 blk(256);
    gemm_bt<u16><<<dim3(8, 4), blk, 0, stream>>>(lat_bf, wq_bf, q_bf, 512, 1024, 1024);
    gemm_bt<u16><<<dim3(16, 256), blk, 0, stream>>>(x_bf, wkv_bf, kvb, 32768, 2048, 1024);
    attn_k<<<128, blk, 0, stream>>>(q_bf, kvb, mask, ao_bf, out + 524288);
    gemm_bt<float><<<dim3(8, 4), blk, 0, stream>>>(ao_bf, wout_bf, out, 512, 1024, 1024);
}

// Round 2
// 526.769 us; speedup vs baseline: 1.1733x; 1.1733x over previous
//
#include <hip/hip_runtime.h>

// PerceiverAttention fused pipeline, bf16 MFMA path.
// b=8 n=4096 m=64 dim=1024 H=16 DH=64 inner=1024
// R2: LDS XOR-swizzle (kill 5e7 bank conflicts), XCD block swizzle on kv GEMM,
//     attention split 128->512 blocks (max / pv / fin).

using u16 = unsigned short;
typedef short bf16x8_t __attribute__((ext_vector_type(8)));
typedef float f32x4_t __attribute__((ext_vector_type(4)));

__device__ __forceinline__ u16 f2bf(float f) {
    union { float f; unsigned u; } v; v.f = f;
    unsigned r = v.u + 0x7fffu + ((v.u >> 16) & 1u);   // RNE
    return (u16)(r >> 16);
}

template <typename T> __device__ __forceinline__ T cvt_out(float v);
template <> __device__ __forceinline__ float cvt_out<float>(float v) { return v; }
template <> __device__ __forceinline__ u16   cvt_out<u16>(float v)   { return f2bf(v); }

// async global->LDS, 16B per lane; lds dest is wave-uniform base + lane*16
__device__ __forceinline__ void cp16(const void* g, void* l) {
    __builtin_amdgcn_global_load_lds((const __attribute__((address_space(1))) unsigned int*)g,
                                     (__attribute__((address_space(3))) unsigned int*)l, 16, 0, 0);
}

// ---------------- fp32 -> bf16 convert (with optional scale) ----------------
__global__ void cvt_bf16(const float* __restrict__ src, u16* __restrict__ dst,
                         int n4, float scale) {
    int i = blockIdx.x * 256 + threadIdx.x;
    if (i >= n4) return;
    float4 v = ((const float4*)src)[i];
    ushort4 o;
    o.x = f2bf(v.x * scale); o.y = f2bf(v.y * scale);
    o.z = f2bf(v.z * scale); o.w = f2bf(v.w * scale);
    ((ushort4*)dst)[i] = o;
}

// ---------------- C[M,N] = A[M,K] * B[N,K]^T, bf16 in, fp32 acc ----------------
// 128x128 tile, BK=64, 4 waves each 64x64.
// LDS layout XOR-swizzled: group g (8 elems) of row r holds global group g^(r&7).
// Staged by fetching swizzled global column per lane (cp16 dest is fixed).
template <typename OutT, bool SWIZ>
__global__ __launch_bounds__(256) void gemm_bt(const u16* __restrict__ A,
                                               const u16* __restrict__ B,
                                               OutT* __restrict__ C,
                                               int M, int N, int K) {
    __shared__ __align__(16) u16 As[128 * 64];
    __shared__ __align__(16) u16 Bs[128 * 64];
    const int tid = threadIdx.x;
    const int wid = tid >> 6, lane = tid & 63;
    int bx = blockIdx.x, by = blockIdx.y;
    if (SWIZ) {
        // kv GEMM only: grid 16 x 256. Per-XCD 8x8 supertiles for L2 reuse.
        int fid = blockIdx.y * 16 + blockIdx.x;
        int xcd = fid & 7, l = fid >> 3;
        int s = l >> 6, w = l & 63;
        int sm = s & 3, sn = s >> 2;
        by = xcd * 32 + sm * 8 + (w >> 3);
        bx = sn * 8 + (w & 7);
    }
    const int bm = by * 128, bn = bx * 128;
    const int srow = lane >> 3;
    const int scol = ((lane & 7) ^ srow) * 8;          // swizzled source column
    const int frow = lane & 15;
    const int wr = (wid >> 1) * 64, wc = (wid & 1) * 64;

    f32x4_t acc[4][4];
#pragma unroll
    for (int i = 0; i < 4; ++i)
#pragma unroll
        for (int j = 0; j < 4; ++j) acc[i][j] = (f32x4_t){0.f, 0.f, 0.f, 0.f};

    for (int k0 = 0; k0 < K; k0 += 64) {
#pragma unroll
        for (int t = 0; t < 4; ++t) {
            const int c = wid * 4 + t;
            const int r = c * 8 + srow;
            cp16(A + (size_t)(bm + r) * K + k0 + scol, As + c * 512);
            cp16(B + (size_t)(bn + r) * K + k0 + scol, Bs + c * 512);
        }
        __syncthreads();
#pragma unroll
        for (int ks = 0; ks < 2; ++ks) {
            const int grp = (((ks * 4 + (lane >> 4)) ^ (frow & 7)) * 8);
            bf16x8_t af[4], bfv[4];
#pragma unroll
            for (int i = 0; i < 4; ++i) {
                af[i]  = *(const bf16x8_t*)(As + (wr + i * 16 + frow) * 64 + grp);
                bfv[i] = *(const bf16x8_t*)(Bs + (wc + i * 16 + frow) * 64 + grp);
            }
#pragma unroll
            for (int i = 0; i < 4; ++i)
#pragma unroll
                for (int j = 0; j < 4; ++j)
                    acc[i][j] = __builtin_amdgcn_mfma_f32_16x16x32_bf16(af[i], bfv[j], acc[i][j], 0, 0, 0);
        }
        __syncthreads();
    }
    const int cr = (lane >> 4) * 4, cc = lane & 15;
#pragma unroll
    for (int i = 0; i < 4; ++i)
#pragma unroll
        for (int j = 0; j < 4; ++j) {
            size_t base = (size_t)(bm + wr + i * 16 + cr) * N + (bn + wc + j * 16 + cc);
#pragma unroll
            for (int r = 0; r < 4; ++r)
                C[base + (size_t)r * N] = cvt_out<OutT>(acc[i][j][r]);
        }
}

// ---------------- attention pass 1: per-chunk row maxes ----------------
// grid 512: block = (bh, chunk of 1024 keys). Mg[(bh*4+c)*64 + m]
__global__ __launch_bounds__(256, 1) void attn_max(const u16* __restrict__ q,
                                                   const u16* __restrict__ kv,
                                                   const int* __restrict__ mask,
                                                   float* __restrict__ Mg) {
    const int c = blockIdx.x & 3, bh = blockIdx.x >> 2, b = bh >> 4, h = bh & 15;
    const int tid = threadIdx.x, wid = tid >> 6, lane = tid & 63;
    const int frow = lane & 15, cr = (lane >> 4) * 4;
    const int srow = lane >> 3, scol = ((lane & 7) ^ srow) * 8;

    __shared__ __align__(16) u16 qs[64 * 64];
    __shared__ __align__(16) u16 ks[256 * 64];
    __shared__ float maskf[256];
    __shared__ float Mpart[4][64];

    const size_t kvbase = (size_t)b * 4096 * 2048 + (size_t)h * 64;

#pragma unroll
    for (int t = 0; t < 2; ++t) {
        int cq = wid * 2 + t;
        int r = cq * 8 + srow;
        cp16(q + (size_t)(b * 64 + r) * 1024 + h * 64 + scol, qs + cq * 512);
    }

    float mloc[16];
#pragma unroll
    for (int i = 0; i < 16; ++i) mloc[i] = -3.0e38f;

    for (int sc = 0; sc < 4; ++sc) {
        const int j0 = c * 1024 + sc * 256;
        __syncthreads();
#pragma unroll
        for (int t = 0; t < 8; ++t) {
            int cs = wid * 8 + t;
            int r = cs * 8 + srow;
            cp16(kv + kvbase + (size_t)(j0 + r) * 2048 + scol, ks + cs * 512);
        }
        maskf[tid] = (mask[b * 4096 + j0 + tid] != 0) ? 1.f : 0.f;
        __syncthreads();

        f32x4_t sacc[4][4];
#pragma unroll
        for (int i = 0; i < 4; ++i)
#pragma unroll
            for (int j = 0; j < 4; ++j) sacc[i][j] = (f32x4_t){0.f, 0.f, 0.f, 0.f};
#pragma unroll
        for (int ks2 = 0; ks2 < 2; ++ks2) {
            const int grp = (((ks2 * 4 + (lane >> 4)) ^ (frow & 7)) * 8);
            bf16x8_t af[4], bfv[4];
#pragma unroll
            for (int i = 0; i < 4; ++i) {
                af[i]  = *(const bf16x8_t*)(qs + (i * 16 + frow) * 64 + grp);
                bfv[i] = *(const bf16x8_t*)(ks + (wid * 64 + i * 16 + frow) * 64 + grp);
            }
#pragma unroll
            for (int i = 0; i < 4; ++i)
#pragma unroll
                for (int j = 0; j < 4; ++j)
                    sacc[i][j] = __builtin_amdgcn_mfma_f32_16x16x32_bf16(af[i], bfv[j], sacc[i][j], 0, 0, 0);
        }
#pragma unroll
        for (int nt = 0; nt < 4; ++nt) {
            const int jl = wid * 64 + nt * 16 + frow;
            if (maskf[jl] < 0.5f) {
#pragma unroll
                for (int mt = 0; mt < 4; ++mt)
#pragma unroll
                    for (int r = 0; r < 4; ++r)
                        mloc[mt * 4 + r] = fmaxf(mloc[mt * 4 + r], sacc[mt][nt][r]);
            }
        }
    }
#pragma unroll
    for (int i = 0; i < 16; ++i) {
        float v = mloc[i];
        v = fmaxf(v, __shfl_xor(v, 1)); v = fmaxf(v, __shfl_xor(v, 2));
        v = fmaxf(v, __shfl_xor(v, 4)); v = fmaxf(v, __shfl_xor(v, 8));
        mloc[i] = v;
    }
    if ((lane & 15) == 0) {
#pragma unroll
        for (int mt = 0; mt < 4; ++mt)
#pragma unroll
            for (int r = 0; r < 4; ++r)
                Mpart[wid][mt * 16 + cr + r] = mloc[mt * 4 + r];
    }
    __syncthreads();
    if (tid < 64)
        Mg[(size_t)(bh * 4 + c) * 64 + tid] =
            fmaxf(fmaxf(Mpart[0][tid], Mpart[1][tid]), fmaxf(Mpart[2][tid], Mpart[3][tid]));
}

// ---------------- attention pass 2: softmax + stats + P@V partials ----------------
__global__ __launch_bounds__(256, 1) void attn_pv(const u16* __restrict__ q,
                                                  const u16* __restrict__ kv,
                                                  const int* __restrict__ mask,
                                                  const float* __restrict__ Mg,
                                                  float* __restrict__ Opart,
                                                  float* __restrict__ Rpart,
                                                  float* __restrict__ loss) {
    const int c = blockIdx.x & 3, bh = blockIdx.x >> 2, b = bh >> 4, h = bh & 15;
    const int tid = threadIdx.x, wid = tid >> 6, lane = tid & 63;
    const int frow = lane & 15, cr = (lane >> 4) * 4;
    const int srow = lane >> 3, scol = ((lane & 7) ^ srow) * 8;

    __shared__ __align__(16) u16 qs[64 * 64];
    __shared__ __align__(16) u16 ks[256 * 64];   // K staging; reused as P and Os
    __shared__ __align__(16) u16 vt[64 * 256];   // swizzled V^T
    __shared__ float maskf[256];
    __shared__ float Mrow[64];
    __shared__ float RpS[4][64];
    __shared__ float lossP[4];

    const size_t kvbase = (size_t)b * 4096 * 2048 + (size_t)h * 64;

#pragma unroll
    for (int t = 0; t < 2; ++t) {
        int cq = wid * 2 + t;
        int r = cq * 8 + srow;
        cp16(q + (size_t)(b * 64 + r) * 1024 + h * 64 + scol, qs + cq * 512);
    }
    if (tid < 64) {
        float m0 = Mg[(size_t)(bh * 4 + 0) * 64 + tid];
        float m1 = Mg[(size_t)(bh * 4 + 1) * 64 + tid];
        float m2 = Mg[(size_t)(bh * 4 + 2) * 64 + tid];
        float m3 = Mg[(size_t)(bh * 4 + 3) * 64 + tid];
        Mrow[tid] = fmaxf(fmaxf(m0, m1), fmaxf(m2, m3));
    }

    f32x4_t oacc[4][4];
#pragma unroll
    for (int i = 0; i < 4; ++i)
#pragma unroll
        for (int j = 0; j < 4; ++j) oacc[i][j] = (f32x4_t){0.f, 0.f, 0.f, 0.f};
    float rloc[16];
#pragma unroll
    for (int i = 0; i < 16; ++i) rloc[i] = 0.f;
    float lossacc = 0.f;

    for (int sc = 0; sc < 4; ++sc) {
        const int j0 = c * 1024 + sc * 256;
        __syncthreads();                           // prev chunk fully consumed
#pragma unroll
        for (int t = 0; t < 8; ++t) {
            int cs = wid * 8 + t;
            int r = cs * 8 + srow;
            cp16(kv + kvbase + (size_t)(j0 + r) * 2048 + scol, ks + cs * 512);
        }
        {   // V^T staging, group-swizzled: vt[d][ (j/8 ^ (d&7))*8 + j%8 ]
            const u16* vrow = kv + kvbase + 1024 + (size_t)(j0 + tid) * 2048;
            const int jhi = tid >> 3, jlo = tid & 7;
#pragma unroll
            for (int p = 0; p < 8; ++p) {
                bf16x8_t v = *(const bf16x8_t*)(vrow + p * 8);
#pragma unroll
                for (int e = 0; e < 8; ++e) {
                    const int d = p * 8 + e;
                    vt[d * 256 + ((jhi ^ (d & 7)) * 8) + jlo] = (u16)v[e];
                }
            }
        }
        maskf[tid] = (mask[b * 4096 + j0 + tid] != 0) ? 1.f : 0.f;
        __syncthreads();

        f32x4_t sacc[4][4];
#pragma unroll
        for (int i = 0; i < 4; ++i)
#pragma unroll
            for (int j = 0; j < 4; ++j) sacc[i][j] = (f32x4_t){0.f, 0.f, 0.f, 0.f};
#pragma unroll
        for (int ks2 = 0; ks2 < 2; ++ks2) {
            const int grp = (((ks2 * 4 + (lane >> 4)) ^ (frow & 7)) * 8);
            bf16x8_t af[4], bfv[4];
#pragma unroll
            for (int i = 0; i < 4; ++i) {
                af[i]  = *(const bf16x8_t*)(qs + (i * 16 + frow) * 64 + grp);
                bfv[i] = *(const bf16x8_t*)(ks + (wid * 64 + i * 16 + frow) * 64 + grp);
            }
#pragma unroll
            for (int i = 0; i < 4; ++i)
#pragma unroll
                for (int j = 0; j < 4; ++j)
                    sacc[i][j] = __builtin_amdgcn_mfma_f32_16x16x32_bf16(af[i], bfv[j], sacc[i][j], 0, 0, 0);
        }
        __syncthreads();                           // all K reads done before P overwrites ks

        // P (bf16) into ks as [m][256] group-swizzled by row; per-column stats
#pragma unroll
        for (int nt = 0; nt < 4; ++nt) {
            const int jl = wid * 64 + nt * 16 + frow;
            const bool msk = maskf[jl] > 0.5f;
            const int jh = jl >> 3, jlo2 = jl & 7;
            float c1 = 0.f, c2 = 0.f;
#pragma unroll
            for (int mt = 0; mt < 4; ++mt) {
#pragma unroll
                for (int r = 0; r < 4; ++r) {
                    const int row = mt * 16 + cr + r;
                    const float t = sacc[mt][nt][r] - Mrow[row];
                    const float p = msk ? 0.f : __expf(t);
                    rloc[mt * 4 + r] += p;
                    c1 += msk ? 0.f : t;
                    c2 += msk ? 0.f : t * t;
                    ks[row * 256 + ((jh ^ (row & 7)) * 8) + jlo2] = f2bf(p);
                }
            }
            c1 += __shfl_xor(c1, 16); c1 += __shfl_xor(c1, 32);
            c2 += __shfl_xor(c2, 16); c2 += __shfl_xor(c2, 32);
            if (lane < 16 && !msk) {
                const float var = (c2 - c1 * c1 * (1.f / 64.f)) * (1.f / 63.f);
                lossacc += fmaxf(1.f - sqrtf(var + 1e-4f), 0.f);
            }
        }
        // P@V over this wave's own 64-key slice (same-wave LDS writes; swizzle
        // keeps each wave's groups inside its own column slice)
#pragma unroll
        for (int ks2 = 0; ks2 < 2; ++ks2) {
            bf16x8_t pa[4], vb[4];
#pragma unroll
            for (int i = 0; i < 4; ++i) {
                const int grp = (((wid * 8 + ks2 * 4 + (lane >> 4)) ^ (frow & 7)) * 8);
                pa[i] = *(const bf16x8_t*)(ks + (i * 16 + frow) * 256 + grp);
                vb[i] = *(const bf16x8_t*)(vt + (i * 16 + frow) * 256 + grp);
            }
#pragma unroll
            for (int i = 0; i < 4; ++i)
#pragma unroll
                for (int j = 0; j < 4; ++j)
                    oacc[i][j] = __builtin_amdgcn_mfma_f32_16x16x32_bf16(pa[i], vb[j], oacc[i][j], 0, 0, 0);
        }
    }

    // ---------- combine waves, write partials ----------
    __syncthreads();
    float* Os = (float*)ks;
    for (int i = tid; i < 4096; i += 256) Os[i] = 0.f;
#pragma unroll
    for (int i = 0; i < 16; ++i) {
        float v = rloc[i];
        v += __shfl_xor(v, 1); v += __shfl_xor(v, 2);
        v += __shfl_xor(v, 4); v += __shfl_xor(v, 8);
        rloc[i] = v;
    }
    if ((lane & 15) == 0) {
#pragma unroll
        for (int mt = 0; mt < 4; ++mt)
#pragma unroll
            for (int r = 0; r < 4; ++r)
                RpS[wid][mt * 16 + cr + r] = rloc[mt * 4 + r];
    }
    __syncthreads();
#pragma unroll
    for (int mt = 0; mt < 4; ++mt)
#pragma unroll
        for (int dt = 0; dt < 4; ++dt)
#pragma unroll
            for (int r = 0; r < 4; ++r)
                atomicAdd(&Os[(mt * 16 + cr + r) * 64 + dt * 16 + frow], oacc[mt][dt][r]);
    __syncthreads();
    const size_t ob = (size_t)(bh * 4 + c) * 4096;
    for (int e = tid; e < 4096; e += 256) Opart[ob + e] = Os[e];
    if (tid < 64)
        Rpart[(size_t)(bh * 4 + c) * 64 + tid] =
            RpS[0][tid] + RpS[1][tid] + RpS[2][tid] + RpS[3][tid];

    float v = lossacc;
    v += __shfl_xor(v, 1); v += __shfl_xor(v, 2); v += __shfl_xor(v, 4);
    v += __shfl_xor(v, 8); v += __shfl_xor(v, 16); v += __shfl_xor(v, 32);
    if (lane == 0) lossP[wid] = v;
    __syncthreads();
    if (tid == 0)
        atomicAdd(loss, (lossP[0] + lossP[1] + lossP[2] + lossP[3]) * (1.f / 524288.f));
}

// ---------------- attention pass 3: combine chunk partials ----------------
__global__ __launch_bounds__(256) void attn_fin(const float* __restrict__ Opart,
                                                const float* __restrict__ Rpart,
                                                u16* __restrict__ ao) {
    const int bh = blockIdx.x, b = bh >> 4, h = bh & 15;
    const int tid = threadIdx.x;
    __shared__ float Rt[64];
    if (tid < 64) {
        float r = 0.f;
#pragma unroll
        for (int cc = 0; cc < 4; ++cc) r += Rpart[(size_t)(bh * 4 + cc) * 64 + tid];
        Rt[tid] = r;
    }
    __syncthreads();
    for (int e = tid; e < 4096; e += 256) {
        float o = 0.f;
#pragma unroll
        for (int cc = 0; cc < 4; ++cc) o += Opart[(size_t)(bh * 4 + cc) * 4096 + e];
        const int row = e >> 6, d = e & 63;
        ao[(size_t)(b * 64 + row) * 1024 + h * 64 + d] = f2bf(o / Rt[row]);
    }
}

// ---------------- host ----------------
extern "C" void kernel_launch(void* const* d_in, const int* in_sizes, int n_in,
                              void* d_out, int out_size, void* d_ws, size_t ws_size,
                              hipStream_t stream) {
    const float* x    = (const float*)d_in[0];
    const float* lat  = (const float*)d_in[1];
    const int*   mask = (const int*)d_in[2];
    const float* Wq   = (const float*)d_in[3];
    const float* Wkv  = (const float*)d_in[4];
    const float* Wout = (const float*)d_in[5];
    float* out = (float*)d_out;

    char* ws = (char*)d_ws;
    u16* x_bf    = (u16*)(ws);                    // 67,108,864 B (reused below)
    u16* kvb     = (u16*)(ws + 67108864);         // 134,217,728 B
    u16* wq_bf   = (u16*)(ws + 201326592);
    u16* wkv_bf  = (u16*)(ws + 203423744);
    u16* wout_bf = (u16*)(ws + 207618048);
    u16* lat_bf  = (u16*)(ws + 209715200);
    u16* q_bf    = (u16*)(ws + 210763776);
    u16* ao_bf   = (u16*)(ws + 211812352);
    // attention partials overlay the x_bf region (x_bf dead after kv GEMM)
    float* Mg    = (float*)(ws);                  // 512*64*4   = 128 KB
    float* Opart = (float*)(ws + 1048576);        // 512*4096*4 = 8 MB
    float* Rpart = (float*)(ws + 1048576 + 8388608);

    hipMemsetAsync(out + 524288, 0, 4, stream);   // zero loss accumulator

    cvt_bf16<<<32768, 256, 0, stream>>>(x, x_bf, 8388608, 1.f);
    cvt_bf16<<<512, 256, 0, stream>>>(lat, lat_bf, 131072, 1.f);
    cvt_bf16<<<1024, 256, 0, stream>>>(Wq, wq_bf, 262144, 0.125f);  // fold dh^-0.5
    cvt_bf16<<<2048, 256, 0, stream>>>(Wkv, wkv_bf, 524288, 1.f);
    cvt_bf16<<<1024, 256, 0, stream>>>(Wout, wout_bf, 262144, 1.f);

    dim3 blk(256);
    gemm_bt<u16, false><<<dim3(8, 4), blk, 0, stream>>>(lat_bf, wq_bf, q_bf, 512, 1024, 1024);
    gemm_bt<u16, true><<<dim3(16, 256), blk, 0, stream>>>(x_bf, wkv_bf, kvb, 32768, 2048, 1024);
    attn_max<<<512, blk, 0, stream>>>(q_bf, kvb, mask, Mg);
    attn_pv<<<512, blk, 0, stream>>>(q_bf, kvb, mask, Mg, Opart, Rpart, out + 524288);
    attn_fin<<<128, blk, 0, stream>>>(Opart, Rpart, ao_bf);
    gemm_bt<float, false><<<dim3(8, 4), blk, 0, stream>>>(ao_bf, wout_bf, out, 512, 1024, 1024);
}

// Round 3
// 518.925 us; speedup vs baseline: 1.1911x; 1.0151x over previous
//
#include <hip/hip_runtime.h>

// PerceiverAttention fused pipeline, bf16 MFMA path.
// b=8 n=4096 m=64 dim=1024 H=16 DH=64 inner=1024
// R3: V written transposed by the GEMM (coalesced LDS-roundtrip epilogue);
//     attn_pv stages V^T via global_load_lds (no scalar transpose);
//     64x64-tile GEMM for q/out (128 blocks); merged weight converts.

using u16 = unsigned short;
typedef short bf16x8_t __attribute__((ext_vector_type(8)));
typedef float f32x4_t __attribute__((ext_vector_type(4)));

__device__ __forceinline__ u16 f2bf(float f) {
    union { float f; unsigned u; } v; v.f = f;
    unsigned r = v.u + 0x7fffu + ((v.u >> 16) & 1u);   // RNE
    return (u16)(r >> 16);
}

template <typename T> __device__ __forceinline__ T cvt_out(float v);
template <> __device__ __forceinline__ float cvt_out<float>(float v) { return v; }
template <> __device__ __forceinline__ u16   cvt_out<u16>(float v)   { return f2bf(v); }

// async global->LDS, 16B per lane; lds dest is wave-uniform base + lane*16
__device__ __forceinline__ void cp16(const void* g, void* l) {
    __builtin_amdgcn_global_load_lds((const __attribute__((address_space(1))) unsigned int*)g,
                                     (__attribute__((address_space(3))) unsigned int*)l, 16, 0, 0);
}

// ---------------- fp32 -> bf16 converts ----------------
__global__ void cvt_bf16(const float* __restrict__ src, u16* __restrict__ dst,
                         int n4, float scale) {
    int i = blockIdx.x * 256 + threadIdx.x;
    if (i >= n4) return;
    float4 v = ((const float4*)src)[i];
    ushort4 o;
    o.x = f2bf(v.x * scale); o.y = f2bf(v.y * scale);
    o.z = f2bf(v.z * scale); o.w = f2bf(v.w * scale);
    ((ushort4*)dst)[i] = o;
}

// merged small converts: lat | Wq(*0.125) | Wkv | Wout (sizes in float4 units)
__global__ void cvt_w(const float* __restrict__ lat, const float* __restrict__ wq,
                      const float* __restrict__ wkv, const float* __restrict__ wout,
                      u16* __restrict__ latb, u16* __restrict__ wqb,
                      u16* __restrict__ wkvb, u16* __restrict__ woutb) {
    int i = blockIdx.x * 256 + threadIdx.x;
    const float* s; u16* d; int off; float sc = 1.f;
    if (i < 131072)      { s = lat;  d = latb;  off = i; }
    else if (i < 393216) { s = wq;   d = wqb;   off = i - 131072; sc = 0.125f; }
    else if (i < 917504) { s = wkv;  d = wkvb;  off = i - 393216; }
    else                 { s = wout; d = woutb; off = i - 917504; }
    float4 v = ((const float4*)s)[off];
    ushort4 o;
    o.x = f2bf(v.x * sc); o.y = f2bf(v.y * sc);
    o.z = f2bf(v.z * sc); o.w = f2bf(v.w * sc);
    ((ushort4*)d)[off] = o;
}

// ---------------- C[M,N] = A[M,K]*B[N,K]^T, 128x128 tile ----------------
// SWIZ=1: 2048-block XCD supertile swizzle (grid 8 x 256).
template <typename OutT, int SWIZ>
__global__ __launch_bounds__(256) void gemm_bt(const u16* __restrict__ A,
                                               const u16* __restrict__ B,
                                               OutT* __restrict__ C,
                                               int M, int N, int K) {
    __shared__ __align__(16) u16 As[128 * 64];
    __shared__ __align__(16) u16 Bs[128 * 64];
    const int tid = threadIdx.x;
    const int wid = tid >> 6, lane = tid & 63;
    int bx = blockIdx.x, by = blockIdx.y;
    if (SWIZ == 1) {
        int fid = blockIdx.y * 8 + blockIdx.x;
        int xcd = fid & 7, l = fid >> 3;
        int s = l >> 6, w = l & 63;
        by = xcd * 32 + s * 8 + (w >> 3);
        bx = w & 7;
    }
    const int bm = by * 128, bn = bx * 128;
    const int srow = lane >> 3;
    const int scol = ((lane & 7) ^ srow) * 8;
    const int frow = lane & 15;
    const int wr = (wid >> 1) * 64, wc = (wid & 1) * 64;

    f32x4_t acc[4][4];
#pragma unroll
    for (int i = 0; i < 4; ++i)
#pragma unroll
        for (int j = 0; j < 4; ++j) acc[i][j] = (f32x4_t){0.f, 0.f, 0.f, 0.f};

    for (int k0 = 0; k0 < K; k0 += 64) {
#pragma unroll
        for (int t = 0; t < 4; ++t) {
            const int c = wid * 4 + t;
            const int r = c * 8 + srow;
            cp16(A + (size_t)(bm + r) * K + k0 + scol, As + c * 512);
            cp16(B + (size_t)(bn + r) * K + k0 + scol, Bs + c * 512);
        }
        __syncthreads();
#pragma unroll
        for (int ks = 0; ks < 2; ++ks) {
            const int grp = (((ks * 4 + (lane >> 4)) ^ (frow & 7)) * 8);
            bf16x8_t af[4], bfv[4];
#pragma unroll
            for (int i = 0; i < 4; ++i) {
                af[i]  = *(const bf16x8_t*)(As + (wr + i * 16 + frow) * 64 + grp);
                bfv[i] = *(const bf16x8_t*)(Bs + (wc + i * 16 + frow) * 64 + grp);
            }
#pragma unroll
            for (int i = 0; i < 4; ++i)
#pragma unroll
                for (int j = 0; j < 4; ++j)
                    acc[i][j] = __builtin_amdgcn_mfma_f32_16x16x32_bf16(af[i], bfv[j], acc[i][j], 0, 0, 0);
        }
        __syncthreads();
    }
    const int cr = (lane >> 4) * 4, cc = lane & 15;
#pragma unroll
    for (int i = 0; i < 4; ++i)
#pragma unroll
        for (int j = 0; j < 4; ++j) {
            size_t base = (size_t)(bm + wr + i * 16 + cr) * N + (bn + wc + j * 16 + cc);
#pragma unroll
            for (int r = 0; r < 4; ++r)
                C[base + (size_t)r * N] = cvt_out<OutT>(acc[i][j][r]);
        }
}

// ---------------- V-half GEMM: writes Vt[(b*16+h)*64+d][4096 j] transposed ----
// A = x_bf (32768,1024), B = Wkv rows 1024..2047. Grid (8,256) swizzled.
__global__ __launch_bounds__(256) void gemm_v(const u16* __restrict__ A,
                                              const u16* __restrict__ B,
                                              u16* __restrict__ Vt, int K) {
    __shared__ __align__(16) u16 As[128 * 64];
    __shared__ __align__(16) u16 Bs[128 * 64];
    __shared__ __align__(16) u16 Ct[128 * 136];   // [vd_local][j_local], pad 136
    const int tid = threadIdx.x;
    const int wid = tid >> 6, lane = tid & 63;
    int fid = blockIdx.y * 8 + blockIdx.x;
    int xcd = fid & 7, l = fid >> 3;
    int s = l >> 6, w = l & 63;
    int by = xcd * 32 + s * 8 + (w >> 3);
    int bx = w & 7;
    const int bm = by * 128, bn = bx * 128;
    const int srow = lane >> 3;
    const int scol = ((lane & 7) ^ srow) * 8;
    const int frow = lane & 15;
    const int wr = (wid >> 1) * 64, wc = (wid & 1) * 64;

    f32x4_t acc[4][4];
#pragma unroll
    for (int i = 0; i < 4; ++i)
#pragma unroll
        for (int j = 0; j < 4; ++j) acc[i][j] = (f32x4_t){0.f, 0.f, 0.f, 0.f};

    for (int k0 = 0; k0 < K; k0 += 64) {
#pragma unroll
        for (int t = 0; t < 4; ++t) {
            const int c = wid * 4 + t;
            const int r = c * 8 + srow;
            cp16(A + (size_t)(bm + r) * K + k0 + scol, As + c * 512);
            cp16(B + (size_t)(bn + r) * K + k0 + scol, Bs + c * 512);
        }
        __syncthreads();
#pragma unroll
        for (int ks = 0; ks < 2; ++ks) {
            const int grp = (((ks * 4 + (lane >> 4)) ^ (frow & 7)) * 8);
            bf16x8_t af[4], bfv[4];
#pragma unroll
            for (int i = 0; i < 4; ++i) {
                af[i]  = *(const bf16x8_t*)(As + (wr + i * 16 + frow) * 64 + grp);
                bfv[i] = *(const bf16x8_t*)(Bs + (wc + i * 16 + frow) * 64 + grp);
            }
#pragma unroll
            for (int i = 0; i < 4; ++i)
#pragma unroll
                for (int j = 0; j < 4; ++j)
                    acc[i][j] = __builtin_amdgcn_mfma_f32_16x16x32_bf16(af[i], bfv[j], acc[i][j], 0, 0, 0);
        }
        __syncthreads();
    }
    // stage transposed into LDS: Ct[vd][j], b64-packed along j (4 rows per pack)
    const int cr = (lane >> 4) * 4, cc = lane & 15;
#pragma unroll
    for (int i = 0; i < 4; ++i)
#pragma unroll
        for (int j = 0; j < 4; ++j) {
            const int vdl = wc + j * 16 + cc;
            const int jl = wr + i * 16 + cr;
            ushort4 pk;
            pk.x = f2bf(acc[i][j][0]); pk.y = f2bf(acc[i][j][1]);
            pk.z = f2bf(acc[i][j][2]); pk.w = f2bf(acc[i][j][3]);
            *(ushort4*)(Ct + vdl * 136 + jl) = pk;
        }
    __syncthreads();
    // coalesced stores: 16 lanes cover one vd-row's 256B of j
    const int b = bm >> 12, jb = bm & 4095, vd0 = bn;
#pragma unroll
    for (int p = 0; p < 8; ++p) {
        const int vdl = p * 16 + (tid >> 4);
        const int jl = (tid & 15) * 8;
        bf16x8_t v = *(const bf16x8_t*)(Ct + vdl * 136 + jl);
        const int vd = vd0 + vdl;
        const size_t addr = ((size_t)(b * 16 + (vd >> 6)) * 64 + (vd & 63)) * 4096 + jb + jl;
        *(bf16x8_t*)(Vt + addr) = v;
    }
}

// ---------------- small GEMM: 64x64 tile, 4 waves of 32x32 ----------------
template <typename OutT>
__global__ __launch_bounds__(256) void gemm_bt64(const u16* __restrict__ A,
                                                 const u16* __restrict__ B,
                                                 OutT* __restrict__ C,
                                                 int M, int N, int K) {
    __shared__ __align__(16) u16 As[64 * 64];
    __shared__ __align__(16) u16 Bs[64 * 64];
    const int tid = threadIdx.x;
    const int wid = tid >> 6, lane = tid & 63;
    const int bm = blockIdx.y * 64, bn = blockIdx.x * 64;
    const int srow = lane >> 3;
    const int scol = ((lane & 7) ^ srow) * 8;
    const int frow = lane & 15;
    const int wr = (wid >> 1) * 32, wc = (wid & 1) * 32;

    f32x4_t acc[2][2];
#pragma unroll
    for (int i = 0; i < 2; ++i)
#pragma unroll
        for (int j = 0; j < 2; ++j) acc[i][j] = (f32x4_t){0.f, 0.f, 0.f, 0.f};

    for (int k0 = 0; k0 < K; k0 += 64) {
#pragma unroll
        for (int t = 0; t < 2; ++t) {
            const int c = wid * 2 + t;
            const int r = c * 8 + srow;
            cp16(A + (size_t)(bm + r) * K + k0 + scol, As + c * 512);
            cp16(B + (size_t)(bn + r) * K + k0 + scol, Bs + c * 512);
        }
        __syncthreads();
#pragma unroll
        for (int ks = 0; ks < 2; ++ks) {
            const int grp = (((ks * 4 + (lane >> 4)) ^ (frow & 7)) * 8);
            bf16x8_t af[2], bfv[2];
#pragma unroll
            for (int i = 0; i < 2; ++i) {
                af[i]  = *(const bf16x8_t*)(As + (wr + i * 16 + frow) * 64 + grp);
                bfv[i] = *(const bf16x8_t*)(Bs + (wc + i * 16 + frow) * 64 + grp);
            }
#pragma unroll
            for (int i = 0; i < 2; ++i)
#pragma unroll
                for (int j = 0; j < 2; ++j)
                    acc[i][j] = __builtin_amdgcn_mfma_f32_16x16x32_bf16(af[i], bfv[j], acc[i][j], 0, 0, 0);
        }
        __syncthreads();
    }
    const int cr = (lane >> 4) * 4, cc = lane & 15;
#pragma unroll
    for (int i = 0; i < 2; ++i)
#pragma unroll
        for (int j = 0; j < 2; ++j) {
            size_t base = (size_t)(bm + wr + i * 16 + cr) * N + (bn + wc + j * 16 + cc);
#pragma unroll
            for (int r = 0; r < 4; ++r)
                C[base + (size_t)r * N] = cvt_out<OutT>(acc[i][j][r]);
        }
}

// ---------------- attention pass 1: per-chunk row maxes ----------------
// kbuf: (32768, 1024) bf16. grid 512 = (bh, chunk of 1024 keys).
__global__ __launch_bounds__(256, 1) void attn_max(const u16* __restrict__ q,
                                                   const u16* __restrict__ kbuf,
                                                   const int* __restrict__ mask,
                                                   float* __restrict__ Mg) {
    const int c = blockIdx.x & 3, bh = blockIdx.x >> 2, b = bh >> 4, h = bh & 15;
    const int tid = threadIdx.x, wid = tid >> 6, lane = tid & 63;
    const int frow = lane & 15, cr = (lane >> 4) * 4;
    const int srow = lane >> 3, scol = ((lane & 7) ^ srow) * 8;

    __shared__ __align__(16) u16 qs[64 * 64];
    __shared__ __align__(16) u16 ks[256 * 64];
    __shared__ float maskf[256];
    __shared__ float Mpart[4][64];

    const size_t kbase = (size_t)b * 4096 * 1024 + (size_t)h * 64;

#pragma unroll
    for (int t = 0; t < 2; ++t) {
        int cq = wid * 2 + t;
        int r = cq * 8 + srow;
        cp16(q + (size_t)(b * 64 + r) * 1024 + h * 64 + scol, qs + cq * 512);
    }

    float mloc[16];
#pragma unroll
    for (int i = 0; i < 16; ++i) mloc[i] = -3.0e38f;

    for (int sc = 0; sc < 4; ++sc) {
        const int j0 = c * 1024 + sc * 256;
        __syncthreads();
#pragma unroll
        for (int t = 0; t < 8; ++t) {
            int cs = wid * 8 + t;
            int r = cs * 8 + srow;
            cp16(kbuf + kbase + (size_t)(j0 + r) * 1024 + scol, ks + cs * 512);
        }
        maskf[tid] = (mask[b * 4096 + j0 + tid] != 0) ? 1.f : 0.f;
        __syncthreads();

        f32x4_t sacc[4][4];
#pragma unroll
        for (int i = 0; i < 4; ++i)
#pragma unroll
            for (int j = 0; j < 4; ++j) sacc[i][j] = (f32x4_t){0.f, 0.f, 0.f, 0.f};
#pragma unroll
        for (int ks2 = 0; ks2 < 2; ++ks2) {
            const int grp = (((ks2 * 4 + (lane >> 4)) ^ (frow & 7)) * 8);
            bf16x8_t af[4], bfv[4];
#pragma unroll
            for (int i = 0; i < 4; ++i) {
                af[i]  = *(const bf16x8_t*)(qs + (i * 16 + frow) * 64 + grp);
                bfv[i] = *(const bf16x8_t*)(ks + (wid * 64 + i * 16 + frow) * 64 + grp);
            }
#pragma unroll
            for (int i = 0; i < 4; ++i)
#pragma unroll
                for (int j = 0; j < 4; ++j)
                    sacc[i][j] = __builtin_amdgcn_mfma_f32_16x16x32_bf16(af[i], bfv[j], sacc[i][j], 0, 0, 0);
        }
#pragma unroll
        for (int nt = 0; nt < 4; ++nt) {
            const int jl = wid * 64 + nt * 16 + frow;
            if (maskf[jl] < 0.5f) {
#pragma unroll
                for (int mt = 0; mt < 4; ++mt)
#pragma unroll
                    for (int r = 0; r < 4; ++r)
                        mloc[mt * 4 + r] = fmaxf(mloc[mt * 4 + r], sacc[mt][nt][r]);
            }
        }
    }
#pragma unroll
    for (int i = 0; i < 16; ++i) {
        float v = mloc[i];
        v = fmaxf(v, __shfl_xor(v, 1)); v = fmaxf(v, __shfl_xor(v, 2));
        v = fmaxf(v, __shfl_xor(v, 4)); v = fmaxf(v, __shfl_xor(v, 8));
        mloc[i] = v;
    }
    if ((lane & 15) == 0) {
#pragma unroll
        for (int mt = 0; mt < 4; ++mt)
#pragma unroll
            for (int r = 0; r < 4; ++r)
                Mpart[wid][mt * 16 + cr + r] = mloc[mt * 4 + r];
    }
    __syncthreads();
    if (tid < 64)
        Mg[(size_t)(bh * 4 + c) * 64 + tid] =
            fmaxf(fmaxf(Mpart[0][tid], Mpart[1][tid]), fmaxf(Mpart[2][tid], Mpart[3][tid]));
}

// ---------------- attention pass 2: softmax + stats + P@V partials ----------------
__global__ __launch_bounds__(256, 1) void attn_pv(const u16* __restrict__ q,
                                                  const u16* __restrict__ kbuf,
                                                  const u16* __restrict__ vtbuf,
                                                  const int* __restrict__ mask,
                                                  const float* __restrict__ Mg,
                                                  float* __restrict__ Opart,
                                                  float* __restrict__ Rpart,
                                                  float* __restrict__ loss) {
    const int c = blockIdx.x & 3, bh = blockIdx.x >> 2, b = bh >> 4, h = bh & 15;
    const int tid = threadIdx.x, wid = tid >> 6, lane = tid & 63;
    const int frow = lane & 15, cr = (lane >> 4) * 4;
    const int srow = lane >> 3, scol = ((lane & 7) ^ srow) * 8;

    __shared__ __align__(16) u16 qs[64 * 64];
    __shared__ __align__(16) u16 ks[256 * 64];    // K staging; reused as P and Os
    __shared__ __align__(16) u16 vts[64 * 256];   // V^T, rows-of-256 swizzled
    __shared__ float maskf[256];
    __shared__ float Mrow[64];
    __shared__ float RpS[4][64];
    __shared__ float lossP[4];

    const size_t kbase = (size_t)b * 4096 * 1024 + (size_t)h * 64;
    const size_t vtbase = (size_t)bh * 64 * 4096;

#pragma unroll
    for (int t = 0; t < 2; ++t) {
        int cq = wid * 2 + t;
        int r = cq * 8 + srow;
        cp16(q + (size_t)(b * 64 + r) * 1024 + h * 64 + scol, qs + cq * 512);
    }
    if (tid < 64) {
        float m0 = Mg[(size_t)(bh * 4 + 0) * 64 + tid];
        float m1 = Mg[(size_t)(bh * 4 + 1) * 64 + tid];
        float m2 = Mg[(size_t)(bh * 4 + 2) * 64 + tid];
        float m3 = Mg[(size_t)(bh * 4 + 3) * 64 + tid];
        Mrow[tid] = fmaxf(fmaxf(m0, m1), fmaxf(m2, m3));
    }

    f32x4_t oacc[4][4];
#pragma unroll
    for (int i = 0; i < 4; ++i)
#pragma unroll
        for (int j = 0; j < 4; ++j) oacc[i][j] = (f32x4_t){0.f, 0.f, 0.f, 0.f};
    float rloc[16];
#pragma unroll
    for (int i = 0; i < 16; ++i) rloc[i] = 0.f;
    float lossacc = 0.f;

    for (int sc = 0; sc < 4; ++sc) {
        const int j0 = c * 1024 + sc * 256;
        __syncthreads();                           // prev chunk fully consumed
#pragma unroll
        for (int t = 0; t < 8; ++t) {
            int cs = wid * 8 + t;
            int r = cs * 8 + srow;
            cp16(kbuf + kbase + (size_t)(j0 + r) * 1024 + scol, ks + cs * 512);
        }
        // V^T staging via cp16: chunk cs = 2 rows of 256; swizzled source col
#pragma unroll
        for (int t = 0; t < 8; ++t) {
            int cs = wid * 8 + t;
            int r = cs * 2 + (lane >> 5);
            int gs = lane & 31;
            cp16(vtbuf + vtbase + (size_t)r * 4096 + j0 + ((gs ^ (r & 7)) * 8),
                 vts + cs * 512);
        }
        maskf[tid] = (mask[b * 4096 + j0 + tid] != 0) ? 1.f : 0.f;
        __syncthreads();

        f32x4_t sacc[4][4];
#pragma unroll
        for (int i = 0; i < 4; ++i)
#pragma unroll
            for (int j = 0; j < 4; ++j) sacc[i][j] = (f32x4_t){0.f, 0.f, 0.f, 0.f};
#pragma unroll
        for (int ks2 = 0; ks2 < 2; ++ks2) {
            const int grp = (((ks2 * 4 + (lane >> 4)) ^ (frow & 7)) * 8);
            bf16x8_t af[4], bfv[4];
#pragma unroll
            for (int i = 0; i < 4; ++i) {
                af[i]  = *(const bf16x8_t*)(qs + (i * 16 + frow) * 64 + grp);
                bfv[i] = *(const bf16x8_t*)(ks + (wid * 64 + i * 16 + frow) * 64 + grp);
            }
#pragma unroll
            for (int i = 0; i < 4; ++i)
#pragma unroll
                for (int j = 0; j < 4; ++j)
                    sacc[i][j] = __builtin_amdgcn_mfma_f32_16x16x32_bf16(af[i], bfv[j], sacc[i][j], 0, 0, 0);
        }
        __syncthreads();                           // all K reads done before P overwrites ks

        // P (bf16) into ks as [m][256], group-swizzled; per-column stats
#pragma unroll
        for (int nt = 0; nt < 4; ++nt) {
            const int jl = wid * 64 + nt * 16 + frow;
            const bool msk = maskf[jl] > 0.5f;
            const int jh = jl >> 3, jlo2 = jl & 7;
            float c1 = 0.f, c2 = 0.f;
#pragma unroll
            for (int mt = 0; mt < 4; ++mt) {
#pragma unroll
                for (int r = 0; r < 4; ++r) {
                    const int row = mt * 16 + cr + r;
                    const float t = sacc[mt][nt][r] - Mrow[row];
                    const float p = msk ? 0.f : __expf(t);
                    rloc[mt * 4 + r] += p;
                    c1 += msk ? 0.f : t;
                    c2 += msk ? 0.f : t * t;
                    ks[row * 256 + ((jh ^ (row & 7)) * 8) + jlo2] = f2bf(p);
                }
            }
            c1 += __shfl_xor(c1, 16); c1 += __shfl_xor(c1, 32);
            c2 += __shfl_xor(c2, 16); c2 += __shfl_xor(c2, 32);
            if (lane < 16 && !msk) {
                const float var = (c2 - c1 * c1 * (1.f / 64.f)) * (1.f / 63.f);
                lossacc += fmaxf(1.f - sqrtf(var + 1e-4f), 0.f);
            }
        }
        // P@V over this wave's own 64-key slice (same-wave LDS data)
#pragma unroll
        for (int ks2 = 0; ks2 < 2; ++ks2) {
            bf16x8_t pa[4], vb[4];
#pragma unroll
            for (int i = 0; i < 4; ++i) {
                const int grp = (((wid * 8 + ks2 * 4 + (lane >> 4)) ^ (frow & 7)) * 8);
                pa[i] = *(const bf16x8_t*)(ks + (i * 16 + frow) * 256 + grp);
                vb[i] = *(const bf16x8_t*)(vts + (i * 16 + frow) * 256 + grp);
            }
#pragma unroll
            for (int i = 0; i < 4; ++i)
#pragma unroll
                for (int j = 0; j < 4; ++j)
                    oacc[i][j] = __builtin_amdgcn_mfma_f32_16x16x32_bf16(pa[i], vb[j], oacc[i][j], 0, 0, 0);
        }
    }

    // ---------- combine waves, write partials ----------
    __syncthreads();
    float* Os = (float*)ks;
    for (int i = tid; i < 4096; i += 256) Os[i] = 0.f;
#pragma unroll
    for (int i = 0; i < 16; ++i) {
        float v = rloc[i];
        v += __shfl_xor(v, 1); v += __shfl_xor(v, 2);
        v += __shfl_xor(v, 4); v += __shfl_xor(v, 8);
        rloc[i] = v;
    }
    if ((lane & 15) == 0) {
#pragma unroll
        for (int mt = 0; mt < 4; ++mt)
#pragma unroll
            for (int r = 0; r < 4; ++r)
                RpS[wid][mt * 16 + cr + r] = rloc[mt * 4 + r];
    }
    __syncthreads();
#pragma unroll
    for (int mt = 0; mt < 4; ++mt)
#pragma unroll
        for (int dt = 0; dt < 4; ++dt)
#pragma unroll
            for (int r = 0; r < 4; ++r)
                atomicAdd(&Os[(mt * 16 + cr + r) * 64 + dt * 16 + frow], oacc[mt][dt][r]);
    __syncthreads();
    const size_t ob = (size_t)(bh * 4 + c) * 4096;
    for (int e = tid; e < 4096; e += 256) Opart[ob + e] = Os[e];
    if (tid < 64)
        Rpart[(size_t)(bh * 4 + c) * 64 + tid] =
            RpS[0][tid] + RpS[1][tid] + RpS[2][tid] + RpS[3][tid];

    float v = lossacc;
    v += __shfl_xor(v, 1); v += __shfl_xor(v, 2); v += __shfl_xor(v, 4);
    v += __shfl_xor(v, 8); v += __shfl_xor(v, 16); v += __shfl_xor(v, 32);
    if (lane == 0) lossP[wid] = v;
    __syncthreads();
    if (tid == 0)
        atomicAdd(loss, (lossP[0] + lossP[1] + lossP[2] + lossP[3]) * (1.f / 524288.f));
}

// ---------------- attention pass 3: combine chunk partials ----------------
__global__ __launch_bounds__(256) void attn_fin(const float* __restrict__ Opart,
                                                const float* __restrict__ Rpart,
                                                u16* __restrict__ ao) {
    const int bh = blockIdx.x, b = bh >> 4, h = bh & 15;
    const int tid = threadIdx.x;
    __shared__ float Rt[64];
    if (tid < 64) {
        float r = 0.f;
#pragma unroll
        for (int cc = 0; cc < 4; ++cc) r += Rpart[(size_t)(bh * 4 + cc) * 64 + tid];
        Rt[tid] = r;
    }
    __syncthreads();
    for (int e = tid; e < 4096; e += 256) {
        float o = 0.f;
#pragma unroll
        for (int cc = 0; cc < 4; ++cc) o += Opart[(size_t)(bh * 4 + cc) * 4096 + e];
        const int row = e >> 6, d = e & 63;
        ao[(size_t)(b * 64 + row) * 1024 + h * 64 + d] = f2bf(o / Rt[row]);
    }
}

// ---------------- host ----------------
extern "C" void kernel_launch(void* const* d_in, const int* in_sizes, int n_in,
                              void* d_out, int out_size, void* d_ws, size_t ws_size,
                              hipStream_t stream) {
    const float* x    = (const float*)d_in[0];
    const float* lat  = (const float*)d_in[1];
    const int*   mask = (const int*)d_in[2];
    const float* Wq   = (const float*)d_in[3];
    const float* Wkv  = (const float*)d_in[4];
    const float* Wout = (const float*)d_in[5];
    float* out = (float*)d_out;

    char* ws = (char*)d_ws;
    u16* x_bf    = (u16*)(ws);                    // 64 MB (reused by partials later)
    u16* kbuf    = (u16*)(ws + 67108864);         // 64 MB: K (32768,1024)
    u16* vtbuf   = (u16*)(ws + 134217728);        // 64 MB: V^T (128 bh,64 d,4096 j)
    u16* wq_bf   = (u16*)(ws + 201326592);
    u16* wkv_bf  = (u16*)(ws + 203423744);
    u16* wout_bf = (u16*)(ws + 207618048);
    u16* lat_bf  = (u16*)(ws + 209715200);
    u16* q_bf    = (u16*)(ws + 210763776);
    u16* ao_bf   = (u16*)(ws + 211812352);
    // attention partials overlay x_bf region (dead after gemm_v)
    float* Mg    = (float*)(ws);                  // 128 KB
    float* Opart = (float*)(ws + 1048576);        // 8 MB
    float* Rpart = (float*)(ws + 1048576 + 8388608);

    hipMemsetAsync(out + 524288, 0, 4, stream);   // zero loss accumulator

    cvt_bf16<<<32768, 256, 0, stream>>>(x, x_bf, 8388608, 1.f);
    cvt_w<<<4608, 256, 0, stream>>>(lat, Wq, Wkv, Wout, lat_bf, wq_bf, wkv_bf, wout_bf);

    dim3 blk(256);
    gemm_bt64<u16><<<dim3(16, 8), blk, 0, stream>>>(lat_bf, wq_bf, q_bf, 512, 1024, 1024);
    gemm_bt<u16, 1><<<dim3(8, 256), blk, 0, stream>>>(x_bf, wkv_bf, kbuf, 32768, 1024, 1024);
    gemm_v<<<dim3(8, 256), blk, 0, stream>>>(x_bf, wkv_bf + 1024 * 1024, vtbuf, 1024);
    attn_max<<<512, blk, 0, stream>>>(q_bf, kbuf, mask, Mg);
    attn_pv<<<512, blk, 0, stream>>>(q_bf, kbuf, vtbuf, mask, Mg, Opart, Rpart, out + 524288);
    attn_fin<<<128, blk, 0, stream>>>(Opart, Rpart, ao_bf);
    gemm_bt64<float><<<dim3(16, 8), blk, 0, stream>>>(ao_bf, wout_bf, out, 512, 1024, 1024);
}

// Round 7
// 486.139 us; speedup vs baseline: 1.2714x; 1.0674x over previous
//
#include <hip/hip_runtime.h>

// PerceiverAttention fused pipeline, bf16 MFMA path.
// b=8 n=4096 m=64 dim=1024 H=16 DH=64 inner=1024
// R7: complete resubmit of the R5 design - barrier-free wave-private attention
//     K-loop (cp16 + wave-local s_waitcnt(0)), fixed float4 epilogue combine,
//     final out-projection GEMM with M=512.

using u16 = unsigned short;
typedef short bf16x8_t __attribute__((ext_vector_type(8)));
typedef float f32x4_t __attribute__((ext_vector_type(4)));

__device__ __forceinline__ u16 f2bf(float f) {
    union { float f; unsigned u; } v; v.f = f;
    unsigned r = v.u + 0x7fffu + ((v.u >> 16) & 1u);   // RNE
    return (u16)(r >> 16);
}

template <typename T> __device__ __forceinline__ T cvt_out(float v);
template <> __device__ __forceinline__ float cvt_out<float>(float v) { return v; }
template <> __device__ __forceinline__ u16   cvt_out<u16>(float v)   { return f2bf(v); }

// async global->LDS, 16B per lane; lds dest is wave-uniform base + lane*16
__device__ __forceinline__ void cp16(const void* g, void* l) {
    __builtin_amdgcn_global_load_lds((const __attribute__((address_space(1))) unsigned int*)g,
                                     (__attribute__((address_space(3))) unsigned int*)l, 16, 0, 0);
}

// ---------------- fp32 -> bf16 converts ----------------
__global__ void cvt_bf16(const float* __restrict__ src, u16* __restrict__ dst,
                         int n4, float scale) {
    int i = blockIdx.x * 256 + threadIdx.x;
    if (i >= n4) return;
    float4 v = ((const float4*)src)[i];
    ushort4 o;
    o.x = f2bf(v.x * scale); o.y = f2bf(v.y * scale);
    o.z = f2bf(v.z * scale); o.w = f2bf(v.w * scale);
    ((ushort4*)dst)[i] = o;
}

// merged small converts: lat | Wq(*0.125) | Wkv | Wout (sizes in float4 units)
__global__ void cvt_w(const float* __restrict__ lat, const float* __restrict__ wq,
                      const float* __restrict__ wkv, const float* __restrict__ wout,
                      u16* __restrict__ latb, u16* __restrict__ wqb,
                      u16* __restrict__ wkvb, u16* __restrict__ woutb) {
    int i = blockIdx.x * 256 + threadIdx.x;
    const float* s; u16* d; int off; float sc = 1.f;
    if (i < 131072)      { s = lat;  d = latb;  off = i; }
    else if (i < 393216) { s = wq;   d = wqb;   off = i - 131072; sc = 0.125f; }
    else if (i < 917504) { s = wkv;  d = wkvb;  off = i - 393216; }
    else                 { s = wout; d = woutb; off = i - 917504; }
    float4 v = ((const float4*)s)[off];
    ushort4 o;
    o.x = f2bf(v.x * sc); o.y = f2bf(v.y * sc);
    o.z = f2bf(v.z * sc); o.w = f2bf(v.w * sc);
    ((ushort4*)d)[off] = o;
}

// ---------------- C[M,N] = A[M,K]*B[N,K]^T, 128x128 tile ----------------
template <typename OutT, int SWIZ>
__global__ __launch_bounds__(256) void gemm_bt(const u16* __restrict__ A,
                                               const u16* __restrict__ B,
                                               OutT* __restrict__ C,
                                               int M, int N, int K) {
    __shared__ __align__(16) u16 As[128 * 64];
    __shared__ __align__(16) u16 Bs[128 * 64];
    const int tid = threadIdx.x;
    const int wid = tid >> 6, lane = tid & 63;
    int bx = blockIdx.x, by = blockIdx.y;
    if (SWIZ == 1) {
        int fid = blockIdx.y * 8 + blockIdx.x;
        int xcd = fid & 7, l = fid >> 3;
        int s = l >> 6, w = l & 63;
        by = xcd * 32 + s * 8 + (w >> 3);
        bx = w & 7;
    }
    const int bm = by * 128, bn = bx * 128;
    const int srow = lane >> 3;
    const int scol = ((lane & 7) ^ srow) * 8;
    const int frow = lane & 15;
    const int wr = (wid >> 1) * 64, wc = (wid & 1) * 64;

    f32x4_t acc[4][4];
#pragma unroll
    for (int i = 0; i < 4; ++i)
#pragma unroll
        for (int j = 0; j < 4; ++j) acc[i][j] = (f32x4_t){0.f, 0.f, 0.f, 0.f};

    for (int k0 = 0; k0 < K; k0 += 64) {
#pragma unroll
        for (int t = 0; t < 4; ++t) {
            const int c = wid * 4 + t;
            const int r = c * 8 + srow;
            cp16(A + (size_t)(bm + r) * K + k0 + scol, As + c * 512);
            cp16(B + (size_t)(bn + r) * K + k0 + scol, Bs + c * 512);
        }
        __syncthreads();
#pragma unroll
        for (int ks = 0; ks < 2; ++ks) {
            const int grp = (((ks * 4 + (lane >> 4)) ^ (frow & 7)) * 8);
            bf16x8_t af[4], bfv[4];
#pragma unroll
            for (int i = 0; i < 4; ++i) {
                af[i]  = *(const bf16x8_t*)(As + (wr + i * 16 + frow) * 64 + grp);
                bfv[i] = *(const bf16x8_t*)(Bs + (wc + i * 16 + frow) * 64 + grp);
            }
#pragma unroll
            for (int i = 0; i < 4; ++i)
#pragma unroll
                for (int j = 0; j < 4; ++j)
                    acc[i][j] = __builtin_amdgcn_mfma_f32_16x16x32_bf16(af[i], bfv[j], acc[i][j], 0, 0, 0);
        }
        __syncthreads();
    }
    const int cr = (lane >> 4) * 4, cc = lane & 15;
#pragma unroll
    for (int i = 0; i < 4; ++i)
#pragma unroll
        for (int j = 0; j < 4; ++j) {
            size_t base = (size_t)(bm + wr + i * 16 + cr) * N + (bn + wc + j * 16 + cc);
#pragma unroll
            for (int r = 0; r < 4; ++r)
                C[base + (size_t)r * N] = cvt_out<OutT>(acc[i][j][r]);
        }
}

// ---------------- V-half GEMM: writes Vt[(b*16+h)*64+d][4096 j] transposed ----
__global__ __launch_bounds__(256) void gemm_v(const u16* __restrict__ A,
                                              const u16* __restrict__ B,
                                              u16* __restrict__ Vt, int K) {
    __shared__ __align__(16) u16 As[128 * 64];
    __shared__ __align__(16) u16 Bs[128 * 64];
    __shared__ __align__(16) u16 Ct[128 * 136];
    const int tid = threadIdx.x;
    const int wid = tid >> 6, lane = tid & 63;
    int fid = blockIdx.y * 8 + blockIdx.x;
    int xcd = fid & 7, l = fid >> 3;
    int s = l >> 6, w = l & 63;
    int by = xcd * 32 + s * 8 + (w >> 3);
    int bx = w & 7;
    const int bm = by * 128, bn = bx * 128;
    const int srow = lane >> 3;
    const int scol = ((lane & 7) ^ srow) * 8;
    const int frow = lane & 15;
    const int wr = (wid >> 1) * 64, wc = (wid & 1) * 64;

    f32x4_t acc[4][4];
#pragma unroll
    for (int i = 0; i < 4; ++i)
#pragma unroll
        for (int j = 0; j < 4; ++j) acc[i][j] = (f32x4_t){0.f, 0.f, 0.f, 0.f};

    for (int k0 = 0; k0 < K; k0 += 64) {
#pragma unroll
        for (int t = 0; t < 4; ++t) {
            const int c = wid * 4 + t;
            const int r = c * 8 + srow;
            cp16(A + (size_t)(bm + r) * K + k0 + scol, As + c * 512);
            cp16(B + (size_t)(bn + r) * K + k0 + scol, Bs + c * 512);
        }
        __syncthreads();
#pragma unroll
        for (int ks = 0; ks < 2; ++ks) {
            const int grp = (((ks * 4 + (lane >> 4)) ^ (frow & 7)) * 8);
            bf16x8_t af[4], bfv[4];
#pragma unroll
            for (int i = 0; i < 4; ++i) {
                af[i]  = *(const bf16x8_t*)(As + (wr + i * 16 + frow) * 64 + grp);
                bfv[i] = *(const bf16x8_t*)(Bs + (wc + i * 16 + frow) * 64 + grp);
            }
#pragma unroll
            for (int i = 0; i < 4; ++i)
#pragma unroll
                for (int j = 0; j < 4; ++j)
                    acc[i][j] = __builtin_amdgcn_mfma_f32_16x16x32_bf16(af[i], bfv[j], acc[i][j], 0, 0, 0);
        }
        __syncthreads();
    }
    const int cr = (lane >> 4) * 4, cc = lane & 15;
#pragma unroll
    for (int i = 0; i < 4; ++i)
#pragma unroll
        for (int j = 0; j < 4; ++j) {
            const int vdl = wc + j * 16 + cc;
            const int jl = wr + i * 16 + cr;
            ushort4 pk;
            pk.x = f2bf(acc[i][j][0]); pk.y = f2bf(acc[i][j][1]);
            pk.z = f2bf(acc[i][j][2]); pk.w = f2bf(acc[i][j][3]);
            *(ushort4*)(Ct + vdl * 136 + jl) = pk;
        }
    __syncthreads();
    const int b = bm >> 12, jb = bm & 4095, vd0 = bn;
#pragma unroll
    for (int p = 0; p < 8; ++p) {
        const int vdl = p * 16 + (tid >> 4);
        const int jl = (tid & 15) * 8;
        bf16x8_t v = *(const bf16x8_t*)(Ct + vdl * 136 + jl);
        const int vd = vd0 + vdl;
        const size_t addr = ((size_t)(b * 16 + (vd >> 6)) * 64 + (vd & 63)) * 4096 + jb + jl;
        *(bf16x8_t*)(Vt + addr) = v;
    }
}

// ---------------- small GEMM: 64x64 tile ----------------
template <typename OutT>
__global__ __launch_bounds__(256) void gemm_bt64(const u16* __restrict__ A,
                                                 const u16* __restrict__ B,
                                                 OutT* __restrict__ C,
                                                 int M, int N, int K) {
    __shared__ __align__(16) u16 As[64 * 64];
    __shared__ __align__(16) u16 Bs[64 * 64];
    const int tid = threadIdx.x;
    const int wid = tid >> 6, lane = tid & 63;
    const int bm = blockIdx.y * 64, bn = blockIdx.x * 64;
    const int srow = lane >> 3;
    const int scol = ((lane & 7) ^ srow) * 8;
    const int frow = lane & 15;
    const int wr = (wid >> 1) * 32, wc = (wid & 1) * 32;

    f32x4_t acc[2][2];
#pragma unroll
    for (int i = 0; i < 2; ++i)
#pragma unroll
        for (int j = 0; j < 2; ++j) acc[i][j] = (f32x4_t){0.f, 0.f, 0.f, 0.f};

    for (int k0 = 0; k0 < K; k0 += 64) {
#pragma unroll
        for (int t = 0; t < 2; ++t) {
            const int c = wid * 2 + t;
            const int r = c * 8 + srow;
            cp16(A + (size_t)(bm + r) * K + k0 + scol, As + c * 512);
            cp16(B + (size_t)(bn + r) * K + k0 + scol, Bs + c * 512);
        }
        __syncthreads();
#pragma unroll
        for (int ks = 0; ks < 2; ++ks) {
            const int grp = (((ks * 4 + (lane >> 4)) ^ (frow & 7)) * 8);
            bf16x8_t af[2], bfv[2];
#pragma unroll
            for (int i = 0; i < 2; ++i) {
                af[i]  = *(const bf16x8_t*)(As + (wr + i * 16 + frow) * 64 + grp);
                bfv[i] = *(const bf16x8_t*)(Bs + (wc + i * 16 + frow) * 64 + grp);
            }
#pragma unroll
            for (int i = 0; i < 2; ++i)
#pragma unroll
                for (int j = 0; j < 2; ++j)
                    acc[i][j] = __builtin_amdgcn_mfma_f32_16x16x32_bf16(af[i], bfv[j], acc[i][j], 0, 0, 0);
        }
        __syncthreads();
    }
    const int cr = (lane >> 4) * 4, cc = lane & 15;
#pragma unroll
    for (int i = 0; i < 2; ++i)
#pragma unroll
        for (int j = 0; j < 2; ++j) {
            size_t base = (size_t)(bm + wr + i * 16 + cr) * N + (bn + wc + j * 16 + cc);
#pragma unroll
            for (int r = 0; r < 4; ++r)
                C[base + (size_t)r * N] = cvt_out<OutT>(acc[i][j][r]);
        }
}

// ---------------- attention pass 1: row maxes, barrier-free waves ----------------
// grid 1024 = (bh, chunk of 512 keys). Mg[(bh*8+c)*64 + m]
__global__ __launch_bounds__(256, 3) void attn_max(const u16* __restrict__ q,
                                                   const u16* __restrict__ kbuf,
                                                   const int* __restrict__ mask,
                                                   float* __restrict__ Mg) {
    const int c = blockIdx.x & 7, bh = blockIdx.x >> 3, b = bh >> 4, h = bh & 15;
    const int tid = threadIdx.x, wid = tid >> 6, lane = tid & 63;
    const int frow = lane & 15, cr = (lane >> 4) * 4;
    const int srow = lane >> 3, scol = ((lane & 7) ^ srow) * 8;

    __shared__ __align__(16) u16 qs[64 * 64];
    __shared__ __align__(16) u16 kw[4][4096];     // wave-private K tiles
    __shared__ float Mpart[4][64];

    const size_t kbase = (size_t)b * 4096 * 1024 + (size_t)h * 64;
    const int cb = c * 512;
    u16* Kw = &kw[wid][0];

#pragma unroll
    for (int t = 0; t < 2; ++t) {
        int cq = wid * 2 + t;
        int r = cq * 8 + srow;
        cp16(q + (size_t)(b * 64 + r) * 1024 + h * 64 + scol, qs + cq * 512);
    }
    __syncthreads();        // qs visible to all waves; only barrier before epilogue

    float mloc[16];
#pragma unroll
    for (int i = 0; i < 16; ++i) mloc[i] = -3.0e38f;

    for (int sc = 0; sc < 2; ++sc) {
        const int j0 = cb + (sc * 4 + wid) * 64;
#pragma unroll
        for (int t = 0; t < 8; ++t) {
            int r = t * 8 + srow;
            cp16(kbuf + kbase + (size_t)(j0 + r) * 1024 + scol, Kw + t * 512);
        }
        __builtin_amdgcn_s_waitcnt(0);            // wave-local drain only

        f32x4_t sacc[4][4];
#pragma unroll
        for (int i = 0; i < 4; ++i)
#pragma unroll
            for (int j = 0; j < 4; ++j) sacc[i][j] = (f32x4_t){0.f, 0.f, 0.f, 0.f};
#pragma unroll
        for (int ks2 = 0; ks2 < 2; ++ks2) {
            const int grp = (((ks2 * 4 + (lane >> 4)) ^ (frow & 7)) * 8);
            bf16x8_t af[4], bfv[4];
#pragma unroll
            for (int i = 0; i < 4; ++i) {
                af[i]  = *(const bf16x8_t*)(qs + (i * 16 + frow) * 64 + grp);
                bfv[i] = *(const bf16x8_t*)(Kw + (i * 16 + frow) * 64 + grp);
            }
#pragma unroll
            for (int i = 0; i < 4; ++i)
#pragma unroll
                for (int j = 0; j < 4; ++j)
                    sacc[i][j] = __builtin_amdgcn_mfma_f32_16x16x32_bf16(af[i], bfv[j], sacc[i][j], 0, 0, 0);
        }
#pragma unroll
        for (int nt = 0; nt < 4; ++nt) {
            const bool msk = mask[b * 4096 + j0 + nt * 16 + frow] != 0;
            if (!msk) {
#pragma unroll
                for (int mt = 0; mt < 4; ++mt)
#pragma unroll
                    for (int r = 0; r < 4; ++r)
                        mloc[mt * 4 + r] = fmaxf(mloc[mt * 4 + r], sacc[mt][nt][r]);
            }
        }
    }
#pragma unroll
    for (int i = 0; i < 16; ++i) {
        float v = mloc[i];
        v = fmaxf(v, __shfl_xor(v, 1)); v = fmaxf(v, __shfl_xor(v, 2));
        v = fmaxf(v, __shfl_xor(v, 4)); v = fmaxf(v, __shfl_xor(v, 8));
        mloc[i] = v;
    }
    if ((lane & 15) == 0) {
#pragma unroll
        for (int mt = 0; mt < 4; ++mt)
#pragma unroll
            for (int r = 0; r < 4; ++r)
                Mpart[wid][mt * 16 + cr + r] = mloc[mt * 4 + r];
    }
    __syncthreads();
    if (tid < 64)
        Mg[(size_t)(bh * 8 + c) * 64 + tid] =
            fmaxf(fmaxf(Mpart[0][tid], Mpart[1][tid]), fmaxf(Mpart[2][tid], Mpart[3][tid]));
}

// ---------------- attention pass 2: softmax+stats+P@V, barrier-free waves ----------------
// grid 512 = (bh, chunk of 1024 keys)
__global__ __launch_bounds__(256, 2) void attn_pv(const u16* __restrict__ q,
                                                  const u16* __restrict__ kbuf,
                                                  const u16* __restrict__ vtbuf,
                                                  const int* __restrict__ mask,
                                                  const float* __restrict__ Mg,
                                                  float* __restrict__ Opart,
                                                  float* __restrict__ Rpart,
                                                  float* __restrict__ loss) {
    const int c = blockIdx.x & 3, bh = blockIdx.x >> 2, b = bh >> 4, h = bh & 15;
    const int tid = threadIdx.x, wid = tid >> 6, lane = tid & 63;
    const int frow = lane & 15, cr = (lane >> 4) * 4;
    const int srow = lane >> 3, scol = ((lane & 7) ^ srow) * 8;

    __shared__ __align__(16) u16 qs[64 * 64];
    __shared__ __align__(16) u16 wbuf[4][2][4096];  // per-wave [K|P][Vt] tiles; Os overlay
    __shared__ float Mrow[64];
    __shared__ float RpS[4][64];
    __shared__ float lossP[4];

    const size_t kbase  = (size_t)b * 4096 * 1024 + (size_t)h * 64;
    const size_t vtbase = (size_t)bh * 64 * 4096;
    const int cb = c * 1024;
    u16* Kw = &wbuf[wid][0][0];
    u16* Vw = &wbuf[wid][1][0];

#pragma unroll
    for (int t = 0; t < 2; ++t) {
        int cq = wid * 2 + t;
        int r = cq * 8 + srow;
        cp16(q + (size_t)(b * 64 + r) * 1024 + h * 64 + scol, qs + cq * 512);
    }
    if (tid < 64) {
        float m = -3.0e38f;
#pragma unroll
        for (int cc = 0; cc < 8; ++cc) m = fmaxf(m, Mg[(size_t)(bh * 8 + cc) * 64 + tid]);
        Mrow[tid] = m;
    }
    __syncthreads();        // qs+Mrow visible; no more block barriers until epilogue

    f32x4_t oacc[4][4];
#pragma unroll
    for (int i = 0; i < 4; ++i)
#pragma unroll
        for (int j = 0; j < 4; ++j) oacc[i][j] = (f32x4_t){0.f, 0.f, 0.f, 0.f};
    float rloc[16];
#pragma unroll
    for (int i = 0; i < 16; ++i) rloc[i] = 0.f;
    float lossacc = 0.f;

    for (int sc = 0; sc < 4; ++sc) {
        const int j0 = cb + (sc * 4 + wid) * 64;
        // wave-private staging: K tile + Vt tile (swizzled source columns)
#pragma unroll
        for (int t = 0; t < 8; ++t) {
            int r = t * 8 + srow;
            cp16(kbuf + kbase + (size_t)(j0 + r) * 1024 + scol, Kw + t * 512);
        }
#pragma unroll
        for (int t = 0; t < 8; ++t) {
            int d = t * 8 + srow;
            cp16(vtbuf + vtbase + (size_t)d * 4096 + j0 + scol, Vw + t * 512);
        }
        __builtin_amdgcn_s_waitcnt(0);            // wave-local drain only

        // QK^T: 64 latents x this wave's 64 keys
        f32x4_t sacc[4][4];
#pragma unroll
        for (int i = 0; i < 4; ++i)
#pragma unroll
            for (int j = 0; j < 4; ++j) sacc[i][j] = (f32x4_t){0.f, 0.f, 0.f, 0.f};
#pragma unroll
        for (int ks2 = 0; ks2 < 2; ++ks2) {
            const int grp = (((ks2 * 4 + (lane >> 4)) ^ (frow & 7)) * 8);
            bf16x8_t af[4], bfv[4];
#pragma unroll
            for (int i = 0; i < 4; ++i) {
                af[i]  = *(const bf16x8_t*)(qs + (i * 16 + frow) * 64 + grp);
                bfv[i] = *(const bf16x8_t*)(Kw + (i * 16 + frow) * 64 + grp);
            }
#pragma unroll
            for (int i = 0; i < 4; ++i)
#pragma unroll
                for (int j = 0; j < 4; ++j)
                    sacc[i][j] = __builtin_amdgcn_mfma_f32_16x16x32_bf16(af[i], bfv[j], sacc[i][j], 0, 0, 0);
        }

        // softmax + variance stats; P overwrites consumed K tile (same wave, in-order LDS)
#pragma unroll
        for (int nt = 0; nt < 4; ++nt) {
            const int jl = nt * 16 + frow;               // local key col 0..63
            const bool msk = mask[b * 4096 + j0 + jl] != 0;
            const int jh = jl >> 3, jlo = jl & 7;
            float c1 = 0.f, c2 = 0.f;
#pragma unroll
            for (int mt = 0; mt < 4; ++mt) {
#pragma unroll
                for (int r = 0; r < 4; ++r) {
                    const int row = mt * 16 + cr + r;
                    const float t = sacc[mt][nt][r] - Mrow[row];
                    const float p = msk ? 0.f : __expf(t);
                    rloc[mt * 4 + r] += p;
                    c1 += msk ? 0.f : t;
                    c2 += msk ? 0.f : t * t;
                    Kw[row * 64 + ((jh ^ (row & 7)) * 8) + jlo] = f2bf(p);
                }
            }
            c1 += __shfl_xor(c1, 16); c1 += __shfl_xor(c1, 32);
            c2 += __shfl_xor(c2, 16); c2 += __shfl_xor(c2, 32);
            if (lane < 16 && !msk) {
                const float var = (c2 - c1 * c1 * (1.f / 64.f)) * (1.f / 63.f);
                lossacc += fmaxf(1.f - sqrtf(var + 1e-4f), 0.f);
            }
        }
        // P@V over this wave's 64 keys
#pragma unroll
        for (int ks2 = 0; ks2 < 2; ++ks2) {
            const int grp = (((ks2 * 4 + (lane >> 4)) ^ (frow & 7)) * 8);
            bf16x8_t pa[4], vb[4];
#pragma unroll
            for (int i = 0; i < 4; ++i) {
                pa[i] = *(const bf16x8_t*)(Kw + (i * 16 + frow) * 64 + grp);
                vb[i] = *(const bf16x8_t*)(Vw + (i * 16 + frow) * 64 + grp);
            }
#pragma unroll
            for (int i = 0; i < 4; ++i)
#pragma unroll
                for (int j = 0; j < 4; ++j)
                    oacc[i][j] = __builtin_amdgcn_mfma_f32_16x16x32_bf16(pa[i], vb[j], oacc[i][j], 0, 0, 0);
        }
    }

    // ---------- per-wave Os regions (own dead K/V space), then combine ----------
    float* Osw = (float*)(&wbuf[0][0][0]) + wid * 4096;
#pragma unroll
    for (int i = 0; i < 4; ++i)
#pragma unroll
        for (int j = 0; j < 4; ++j)
#pragma unroll
            for (int r = 0; r < 4; ++r)
                Osw[(i * 16 + cr + r) * 64 + j * 16 + frow] = oacc[i][j][r];

#pragma unroll
    for (int i = 0; i < 16; ++i) {
        float v = rloc[i];
        v += __shfl_xor(v, 1); v += __shfl_xor(v, 2);
        v += __shfl_xor(v, 4); v += __shfl_xor(v, 8);
        rloc[i] = v;
    }
    if ((lane & 15) == 0) {
#pragma unroll
        for (int mt = 0; mt < 4; ++mt)
#pragma unroll
            for (int r = 0; r < 4; ++r)
                RpS[wid][mt * 16 + cr + r] = rloc[mt * 4 + r];
    }
    float v = lossacc;
    v += __shfl_xor(v, 1); v += __shfl_xor(v, 2); v += __shfl_xor(v, 4);
    v += __shfl_xor(v, 8); v += __shfl_xor(v, 16); v += __shfl_xor(v, 32);
    if (lane == 0) lossP[wid] = v;
    __syncthreads();

    const float4* Ob4 = (const float4*)(&wbuf[0][0][0]);
    const size_t ob = (size_t)(bh * 4 + c) * 4096;
#pragma unroll
    for (int p = 0; p < 4; ++p) {
        const int e = tid + p * 256;          // float4 index 0..1023 within a 4096-f tile
        float4 s0 = Ob4[e];
        float4 s1 = Ob4[e + 1024];
        float4 s2 = Ob4[e + 2048];
        float4 s3 = Ob4[e + 3072];
        float4 o;
        o.x = s0.x + s1.x + s2.x + s3.x;
        o.y = s0.y + s1.y + s2.y + s3.y;
        o.z = s0.z + s1.z + s2.z + s3.z;
        o.w = s0.w + s1.w + s2.w + s3.w;
        ((float4*)(Opart + ob))[e] = o;
    }
    if (tid < 64)
        Rpart[(size_t)(bh * 4 + c) * 64 + tid] =
            RpS[0][tid] + RpS[1][tid] + RpS[2][tid] + RpS[3][tid];
    if (tid == 0)
        atomicAdd(loss, (lossP[0] + lossP[1] + lossP[2] + lossP[3]) * (1.f / 524288.f));
}

// ---------------- attention pass 3: combine chunk partials ----------------
__global__ __launch_bounds__(256) void attn_fin(const float* __restrict__ Opart,
                                                const float* __restrict__ Rpart,
                                                u16* __restrict__ ao) {
    const int bh = blockIdx.x, b = bh >> 4, h = bh & 15;
    const int tid = threadIdx.x;
    __shared__ float Rt[64];
    if (tid < 64) {
        float r = 0.f;
#pragma unroll
        for (int cc = 0; cc < 4; ++cc) r += Rpart[(size_t)(bh * 4 + cc) * 64 + tid];
        Rt[tid] = r;
    }
    __syncthreads();
    for (int e = tid; e < 4096; e += 256) {
        float o = 0.f;
#pragma unroll
        for (int cc = 0; cc < 4; ++cc) o += Opart[(size_t)(bh * 4 + cc) * 4096 + e];
        const int row = e >> 6, d = e & 63;
        ao[(size_t)(b * 64 + row) * 1024 + h * 64 + d] = f2bf(o / Rt[row]);
    }
}

// ---------------- host ----------------
extern "C" void kernel_launch(void* const* d_in, const int* in_sizes, int n_in,
                              void* d_out, int out_size, void* d_ws, size_t ws_size,
                              hipStream_t stream) {
    const float* x    = (const float*)d_in[0];
    const float* lat  = (const float*)d_in[1];
    const int*   mask = (const int*)d_in[2];
    const float* Wq   = (const float*)d_in[3];
    const float* Wkv  = (const float*)d_in[4];
    const float* Wout = (const float*)d_in[5];
    float* out = (float*)d_out;

    char* ws = (char*)d_ws;
    u16* x_bf    = (u16*)(ws);                    // 64 MB (reused by partials later)
    u16* kbuf    = (u16*)(ws + 67108864);         // 64 MB: K (32768,1024)
    u16* vtbuf   = (u16*)(ws + 134217728);        // 64 MB: V^T (128 bh,64 d,4096 j)
    u16* wq_bf   = (u16*)(ws + 201326592);
    u16* wkv_bf  = (u16*)(ws + 203423744);
    u16* wout_bf = (u16*)(ws + 207618048);
    u16* lat_bf  = (u16*)(ws + 209715200);
    u16* q_bf    = (u16*)(ws + 210763776);
    u16* ao_bf   = (u16*)(ws + 211812352);
    // attention partials overlay x_bf region (dead after gemm_v)
    float* Mg    = (float*)(ws);                  // 1024*64*4 = 256 KB
    float* Opart = (float*)(ws + 1048576);        // 8 MB
    float* Rpart = (float*)(ws + 1048576 + 8388608);

    hipMemsetAsync(out + 524288, 0, 4, stream);   // zero loss accumulator

    cvt_bf16<<<32768, 256, 0, stream>>>(x, x_bf, 8388608, 1.f);
    cvt_w<<<4608, 256, 0, stream>>>(lat, Wq, Wkv, Wout, lat_bf, wq_bf, wkv_bf, wout_bf);

    dim3 blk(256);
    gemm_bt64<u16><<<dim3(16, 8), blk, 0, stream>>>(lat_bf, wq_bf, q_bf, 512, 1024, 1024);
    gemm_bt<u16, 1><<<dim3(8, 256), blk, 0, stream>>>(x_bf, wkv_bf, kbuf, 32768, 1024, 1024);
    gemm_v<<<dim3(8, 256), blk, 0, stream>>>(x_bf, wkv_bf + 1024 * 1024, vtbuf, 1024);
    attn_max<<<1024, blk, 0, stream>>>(q_bf, kbuf, mask, Mg);
    attn_pv<<<512, blk, 0, stream>>>(q_bf, kbuf, vtbuf, mask, Mg, Opart, Rpart, out + 524288);
    attn_fin<<<128, blk, 0, stream>>>(Opart, Rpart, ao_bf);
    gemm_bt64<float><<<dim3(16, 8), blk, 0, stream>>>(ao_bf, wout_bf, out, 512, 1024, 1024);
}

// Round 8
// 471.161 us; speedup vs baseline: 1.3118x; 1.0318x over previous
//
#include <hip/hip_runtime.h>

// PerceiverAttention fused pipeline, bf16 MFMA path.
// b=8 n=4096 m=64 dim=1024 H=16 DH=64 inner=1024
// R8: merged K/V GEMM (one A pass, N=2048, XCD supertile swizzle) with the
//     V-transpose epilogue overlaid on dead As/Bs in two 64-row phases
//     (LDS stays 32 KB -> full occupancy); merged converts into one launch.

using u16 = unsigned short;
typedef short bf16x8_t __attribute__((ext_vector_type(8)));
typedef float f32x4_t __attribute__((ext_vector_type(4)));

__device__ __forceinline__ u16 f2bf(float f) {
    union { float f; unsigned u; } v; v.f = f;
    unsigned r = v.u + 0x7fffu + ((v.u >> 16) & 1u);   // RNE
    return (u16)(r >> 16);
}

template <typename T> __device__ __forceinline__ T cvt_out(float v);
template <> __device__ __forceinline__ float cvt_out<float>(float v) { return v; }
template <> __device__ __forceinline__ u16   cvt_out<u16>(float v)   { return f2bf(v); }

// async global->LDS, 16B per lane; lds dest is wave-uniform base + lane*16
__device__ __forceinline__ void cp16(const void* g, void* l) {
    __builtin_amdgcn_global_load_lds((const __attribute__((address_space(1))) unsigned int*)g,
                                     (__attribute__((address_space(3))) unsigned int*)l, 16, 0, 0);
}

// ---------------- fp32 -> bf16 converts, all inputs in one launch ----------------
// float4 ranges: x 8388608 | lat 131072 | Wq 262144 (*0.125) | Wkv 524288 | Wout 262144
__global__ void cvt_all(const float* __restrict__ x, const float* __restrict__ lat,
                        const float* __restrict__ wq, const float* __restrict__ wkv,
                        const float* __restrict__ wout,
                        u16* __restrict__ xb, u16* __restrict__ latb,
                        u16* __restrict__ wqb, u16* __restrict__ wkvb,
                        u16* __restrict__ woutb) {
    int i = blockIdx.x * 256 + threadIdx.x;
    const float* s; u16* d; int off; float sc = 1.f;
    if (i < 8388608)      { s = x;    d = xb;    off = i; }
    else if (i < 8519680) { s = lat;  d = latb;  off = i - 8388608; }
    else if (i < 8781824) { s = wq;   d = wqb;   off = i - 8519680; sc = 0.125f; }
    else if (i < 9306112) { s = wkv;  d = wkvb;  off = i - 8781824; }
    else if (i < 9568256) { s = wout; d = woutb; off = i - 9306112; }
    else return;
    float4 v = ((const float4*)s)[off];
    ushort4 o;
    o.x = f2bf(v.x * sc); o.y = f2bf(v.y * sc);
    o.z = f2bf(v.z * sc); o.w = f2bf(v.w * sc);
    ((ushort4*)d)[off] = o;
}

// ---------------- merged KV GEMM ----------------
// A = x_bf (32768,1024); B = wkv_bf (2048,1024). Grid (16,256), R2 swizzle.
// bx<8: K-half -> kbuf[(bm+r)*1024 + bx*128 + c] (bf16)
// bx>=8: V-half -> Vt[((b*16+h)*64+d)*4096 + j] transposed via 2-phase LDS overlay
__global__ __launch_bounds__(256) void gemm_kv(const u16* __restrict__ A,
                                               const u16* __restrict__ B,
                                               u16* __restrict__ Kc,
                                               u16* __restrict__ Vt) {
    __shared__ __align__(16) u16 smem[16384];     // As | Bs; epilogue overlays Ct
    u16* As = smem;
    u16* Bs = smem + 8192;
    const int tid = threadIdx.x;
    const int wid = tid >> 6, lane = tid & 63;
    // supertile swizzle (R2): per-XCD 8x8 block groups over a 4x2 super-grid
    int fid = blockIdx.y * 16 + blockIdx.x;
    int xcd = fid & 7, l = fid >> 3;
    int s = l >> 6, w = l & 63;
    int sm = s & 3, sn = s >> 2;
    int by = xcd * 32 + sm * 8 + (w >> 3);
    int bx = sn * 8 + (w & 7);
    const int bm = by * 128, bn = bx * 128;
    const int K = 1024;
    const int srow = lane >> 3;
    const int scol = ((lane & 7) ^ srow) * 8;
    const int frow = lane & 15;
    const int wr = (wid >> 1) * 64, wc = (wid & 1) * 64;

    f32x4_t acc[4][4];
#pragma unroll
    for (int i = 0; i < 4; ++i)
#pragma unroll
        for (int j = 0; j < 4; ++j) acc[i][j] = (f32x4_t){0.f, 0.f, 0.f, 0.f};

    for (int k0 = 0; k0 < K; k0 += 64) {
#pragma unroll
        for (int t = 0; t < 4; ++t) {
            const int c = wid * 4 + t;
            const int r = c * 8 + srow;
            cp16(A + (size_t)(bm + r) * K + k0 + scol, As + c * 512);
            cp16(B + (size_t)(bn + r) * K + k0 + scol, Bs + c * 512);
        }
        __syncthreads();
#pragma unroll
        for (int ks = 0; ks < 2; ++ks) {
            const int grp = (((ks * 4 + (lane >> 4)) ^ (frow & 7)) * 8);
            bf16x8_t af[4], bfv[4];
#pragma unroll
            for (int i = 0; i < 4; ++i) {
                af[i]  = *(const bf16x8_t*)(As + (wr + i * 16 + frow) * 64 + grp);
                bfv[i] = *(const bf16x8_t*)(Bs + (wc + i * 16 + frow) * 64 + grp);
            }
#pragma unroll
            for (int i = 0; i < 4; ++i)
#pragma unroll
                for (int j = 0; j < 4; ++j)
                    acc[i][j] = __builtin_amdgcn_mfma_f32_16x16x32_bf16(af[i], bfv[j], acc[i][j], 0, 0, 0);
        }
        __syncthreads();
    }
    const int cr = (lane >> 4) * 4, cc = lane & 15;

    if (bx < 8) {
        // K-half: plain bf16 store, row-major N=1024
#pragma unroll
        for (int i = 0; i < 4; ++i)
#pragma unroll
            for (int j = 0; j < 4; ++j) {
                size_t base = (size_t)(bm + wr + i * 16 + cr) * 1024 + (bn + wc + j * 16 + cc);
#pragma unroll
                for (int r = 0; r < 4; ++r)
                    Kc[base + (size_t)r * 1024] = f2bf(acc[i][j][r]);
            }
        return;
    }

    // V-half: transpose epilogue, 2 phases of 64 vd-rows overlaid on smem
    const int vd0 = bn - 1024;
    const int b = bm >> 12, jb = bm & 4095;
    u16* Ct = smem;                                // 64 x 136 u16 = 17408 B
#pragma unroll
    for (int ph = 0; ph < 2; ++ph) {
        __syncthreads();                           // smem free (or prev phase done)
        if ((wid & 1) == ph) {                     // waves holding wc == ph*64
#pragma unroll
            for (int i = 0; i < 4; ++i)
#pragma unroll
                for (int j = 0; j < 4; ++j) {
                    const int vdl = j * 16 + cc;   // 0..63 within phase
                    const int jl = wr + i * 16 + cr;
                    ushort4 pk;
                    pk.x = f2bf(acc[i][j][0]); pk.y = f2bf(acc[i][j][1]);
                    pk.z = f2bf(acc[i][j][2]); pk.w = f2bf(acc[i][j][3]);
                    *(ushort4*)(Ct + vdl * 136 + jl) = pk;
                }
        }
        __syncthreads();
        // 64 rows x 128 j = 1024 vec8 stores, 4 per thread, coalesced in j
#pragma unroll
        for (int p = 0; p < 4; ++p) {
            const int idx = p * 256 + tid;         // 0..1023
            const int vdl = idx >> 4;
            const int jl = (idx & 15) * 8;
            bf16x8_t v = *(const bf16x8_t*)(Ct + vdl * 136 + jl);
            const int vd = vd0 + ph * 64 + vdl;
            const size_t addr = ((size_t)(b * 16 + (vd >> 6)) * 64 + (vd & 63)) * 4096 + jb + jl;
            *(bf16x8_t*)(Vt + addr) = v;
        }
    }
}

// ---------------- small GEMM: 64x64 tile ----------------
template <typename OutT>
__global__ __launch_bounds__(256) void gemm_bt64(const u16* __restrict__ A,
                                                 const u16* __restrict__ B,
                                                 OutT* __restrict__ C,
                                                 int M, int N, int K) {
    __shared__ __align__(16) u16 As[64 * 64];
    __shared__ __align__(16) u16 Bs[64 * 64];
    const int tid = threadIdx.x;
    const int wid = tid >> 6, lane = tid & 63;
    const int bm = blockIdx.y * 64, bn = blockIdx.x * 64;
    const int srow = lane >> 3;
    const int scol = ((lane & 7) ^ srow) * 8;
    const int frow = lane & 15;
    const int wr = (wid >> 1) * 32, wc = (wid & 1) * 32;

    f32x4_t acc[2][2];
#pragma unroll
    for (int i = 0; i < 2; ++i)
#pragma unroll
        for (int j = 0; j < 2; ++j) acc[i][j] = (f32x4_t){0.f, 0.f, 0.f, 0.f};

    for (int k0 = 0; k0 < K; k0 += 64) {
#pragma unroll
        for (int t = 0; t < 2; ++t) {
            const int c = wid * 2 + t;
            const int r = c * 8 + srow;
            cp16(A + (size_t)(bm + r) * K + k0 + scol, As + c * 512);
            cp16(B + (size_t)(bn + r) * K + k0 + scol, Bs + c * 512);
        }
        __syncthreads();
#pragma unroll
        for (int ks = 0; ks < 2; ++ks) {
            const int grp = (((ks * 4 + (lane >> 4)) ^ (frow & 7)) * 8);
            bf16x8_t af[2], bfv[2];
#pragma unroll
            for (int i = 0; i < 2; ++i) {
                af[i]  = *(const bf16x8_t*)(As + (wr + i * 16 + frow) * 64 + grp);
                bfv[i] = *(const bf16x8_t*)(Bs + (wc + i * 16 + frow) * 64 + grp);
            }
#pragma unroll
            for (int i = 0; i < 2; ++i)
#pragma unroll
                for (int j = 0; j < 2; ++j)
                    acc[i][j] = __builtin_amdgcn_mfma_f32_16x16x32_bf16(af[i], bfv[j], acc[i][j], 0, 0, 0);
        }
        __syncthreads();
    }
    const int cr = (lane >> 4) * 4, cc = lane & 15;
#pragma unroll
    for (int i = 0; i < 2; ++i)
#pragma unroll
        for (int j = 0; j < 2; ++j) {
            size_t base = (size_t)(bm + wr + i * 16 + cr) * N + (bn + wc + j * 16 + cc);
#pragma unroll
            for (int r = 0; r < 4; ++r)
                C[base + (size_t)r * N] = cvt_out<OutT>(acc[i][j][r]);
        }
}

// ---------------- attention pass 1: row maxes, barrier-free waves ----------------
// grid 1024 = (bh, chunk of 512 keys). Mg[(bh*8+c)*64 + m]
__global__ __launch_bounds__(256, 3) void attn_max(const u16* __restrict__ q,
                                                   const u16* __restrict__ kbuf,
                                                   const int* __restrict__ mask,
                                                   float* __restrict__ Mg) {
    const int c = blockIdx.x & 7, bh = blockIdx.x >> 3, b = bh >> 4, h = bh & 15;
    const int tid = threadIdx.x, wid = tid >> 6, lane = tid & 63;
    const int frow = lane & 15, cr = (lane >> 4) * 4;
    const int srow = lane >> 3, scol = ((lane & 7) ^ srow) * 8;

    __shared__ __align__(16) u16 qs[64 * 64];
    __shared__ __align__(16) u16 kw[4][4096];     // wave-private K tiles
    __shared__ float Mpart[4][64];

    const size_t kbase = (size_t)b * 4096 * 1024 + (size_t)h * 64;
    const int cb = c * 512;
    u16* Kw = &kw[wid][0];

#pragma unroll
    for (int t = 0; t < 2; ++t) {
        int cq = wid * 2 + t;
        int r = cq * 8 + srow;
        cp16(q + (size_t)(b * 64 + r) * 1024 + h * 64 + scol, qs + cq * 512);
    }
    __syncthreads();        // qs visible to all waves

    float mloc[16];
#pragma unroll
    for (int i = 0; i < 16; ++i) mloc[i] = -3.0e38f;

    for (int sc = 0; sc < 2; ++sc) {
        const int j0 = cb + (sc * 4 + wid) * 64;
#pragma unroll
        for (int t = 0; t < 8; ++t) {
            int r = t * 8 + srow;
            cp16(kbuf + kbase + (size_t)(j0 + r) * 1024 + scol, Kw + t * 512);
        }
        __builtin_amdgcn_s_waitcnt(0);            // wave-local drain only

        f32x4_t sacc[4][4];
#pragma unroll
        for (int i = 0; i < 4; ++i)
#pragma unroll
            for (int j = 0; j < 4; ++j) sacc[i][j] = (f32x4_t){0.f, 0.f, 0.f, 0.f};
#pragma unroll
        for (int ks2 = 0; ks2 < 2; ++ks2) {
            const int grp = (((ks2 * 4 + (lane >> 4)) ^ (frow & 7)) * 8);
            bf16x8_t af[4], bfv[4];
#pragma unroll
            for (int i = 0; i < 4; ++i) {
                af[i]  = *(const bf16x8_t*)(qs + (i * 16 + frow) * 64 + grp);
                bfv[i] = *(const bf16x8_t*)(Kw + (i * 16 + frow) * 64 + grp);
            }
#pragma unroll
            for (int i = 0; i < 4; ++i)
#pragma unroll
                for (int j = 0; j < 4; ++j)
                    sacc[i][j] = __builtin_amdgcn_mfma_f32_16x16x32_bf16(af[i], bfv[j], sacc[i][j], 0, 0, 0);
        }
#pragma unroll
        for (int nt = 0; nt < 4; ++nt) {
            const bool msk = mask[b * 4096 + j0 + nt * 16 + frow] != 0;
            if (!msk) {
#pragma unroll
                for (int mt = 0; mt < 4; ++mt)
#pragma unroll
                    for (int r = 0; r < 4; ++r)
                        mloc[mt * 4 + r] = fmaxf(mloc[mt * 4 + r], sacc[mt][nt][r]);
            }
        }
    }
#pragma unroll
    for (int i = 0; i < 16; ++i) {
        float v = mloc[i];
        v = fmaxf(v, __shfl_xor(v, 1)); v = fmaxf(v, __shfl_xor(v, 2));
        v = fmaxf(v, __shfl_xor(v, 4)); v = fmaxf(v, __shfl_xor(v, 8));
        mloc[i] = v;
    }
    if ((lane & 15) == 0) {
#pragma unroll
        for (int mt = 0; mt < 4; ++mt)
#pragma unroll
            for (int r = 0; r < 4; ++r)
                Mpart[wid][mt * 16 + cr + r] = mloc[mt * 4 + r];
    }
    __syncthreads();
    if (tid < 64)
        Mg[(size_t)(bh * 8 + c) * 64 + tid] =
            fmaxf(fmaxf(Mpart[0][tid], Mpart[1][tid]), fmaxf(Mpart[2][tid], Mpart[3][tid]));
}

// ---------------- attention pass 2: softmax+stats+P@V, barrier-free waves ----------------
// grid 512 = (bh, chunk of 1024 keys)
__global__ __launch_bounds__(256, 2) void attn_pv(const u16* __restrict__ q,
                                                  const u16* __restrict__ kbuf,
                                                  const u16* __restrict__ vtbuf,
                                                  const int* __restrict__ mask,
                                                  const float* __restrict__ Mg,
                                                  float* __restrict__ Opart,
                                                  float* __restrict__ Rpart,
                                                  float* __restrict__ loss) {
    const int c = blockIdx.x & 3, bh = blockIdx.x >> 2, b = bh >> 4, h = bh & 15;
    const int tid = threadIdx.x, wid = tid >> 6, lane = tid & 63;
    const int frow = lane & 15, cr = (lane >> 4) * 4;
    const int srow = lane >> 3, scol = ((lane & 7) ^ srow) * 8;

    __shared__ __align__(16) u16 qs[64 * 64];
    __shared__ __align__(16) u16 wbuf[4][2][4096];  // per-wave [K|P][Vt] tiles; Os overlay
    __shared__ float Mrow[64];
    __shared__ float RpS[4][64];
    __shared__ float lossP[4];

    const size_t kbase  = (size_t)b * 4096 * 1024 + (size_t)h * 64;
    const size_t vtbase = (size_t)bh * 64 * 4096;
    const int cb = c * 1024;
    u16* Kw = &wbuf[wid][0][0];
    u16* Vw = &wbuf[wid][1][0];

#pragma unroll
    for (int t = 0; t < 2; ++t) {
        int cq = wid * 2 + t;
        int r = cq * 8 + srow;
        cp16(q + (size_t)(b * 64 + r) * 1024 + h * 64 + scol, qs + cq * 512);
    }
    if (tid < 64) {
        float m = -3.0e38f;
#pragma unroll
        for (int cc = 0; cc < 8; ++cc) m = fmaxf(m, Mg[(size_t)(bh * 8 + cc) * 64 + tid]);
        Mrow[tid] = m;
    }
    __syncthreads();        // qs+Mrow visible; no more block barriers until epilogue

    f32x4_t oacc[4][4];
#pragma unroll
    for (int i = 0; i < 4; ++i)
#pragma unroll
        for (int j = 0; j < 4; ++j) oacc[i][j] = (f32x4_t){0.f, 0.f, 0.f, 0.f};
    float rloc[16];
#pragma unroll
    for (int i = 0; i < 16; ++i) rloc[i] = 0.f;
    float lossacc = 0.f;

    for (int sc = 0; sc < 4; ++sc) {
        const int j0 = cb + (sc * 4 + wid) * 64;
        // wave-private staging: K tile + Vt tile (swizzled source columns)
#pragma unroll
        for (int t = 0; t < 8; ++t) {
            int r = t * 8 + srow;
            cp16(kbuf + kbase + (size_t)(j0 + r) * 1024 + scol, Kw + t * 512);
        }
#pragma unroll
        for (int t = 0; t < 8; ++t) {
            int d = t * 8 + srow;
            cp16(vtbuf + vtbase + (size_t)d * 4096 + j0 + scol, Vw + t * 512);
        }
        __builtin_amdgcn_s_waitcnt(0);            // wave-local drain only

        // QK^T: 64 latents x this wave's 64 keys
        f32x4_t sacc[4][4];
#pragma unroll
        for (int i = 0; i < 4; ++i)
#pragma unroll
            for (int j = 0; j < 4; ++j) sacc[i][j] = (f32x4_t){0.f, 0.f, 0.f, 0.f};
#pragma unroll
        for (int ks2 = 0; ks2 < 2; ++ks2) {
            const int grp = (((ks2 * 4 + (lane >> 4)) ^ (frow & 7)) * 8);
            bf16x8_t af[4], bfv[4];
#pragma unroll
            for (int i = 0; i < 4; ++i) {
                af[i]  = *(const bf16x8_t*)(qs + (i * 16 + frow) * 64 + grp);
                bfv[i] = *(const bf16x8_t*)(Kw + (i * 16 + frow) * 64 + grp);
            }
#pragma unroll
            for (int i = 0; i < 4; ++i)
#pragma unroll
                for (int j = 0; j < 4; ++j)
                    sacc[i][j] = __builtin_amdgcn_mfma_f32_16x16x32_bf16(af[i], bfv[j], sacc[i][j], 0, 0, 0);
        }

        // softmax + variance stats; P overwrites consumed K tile (same wave, in-order LDS)
#pragma unroll
        for (int nt = 0; nt < 4; ++nt) {
            const int jl = nt * 16 + frow;               // local key col 0..63
            const bool msk = mask[b * 4096 + j0 + jl] != 0;
            const int jh = jl >> 3, jlo = jl & 7;
            float c1 = 0.f, c2 = 0.f;
#pragma unroll
            for (int mt = 0; mt < 4; ++mt) {
#pragma unroll
                for (int r = 0; r < 4; ++r) {
                    const int row = mt * 16 + cr + r;
                    const float t = sacc[mt][nt][r] - Mrow[row];
                    const float p = msk ? 0.f : __expf(t);
                    rloc[mt * 4 + r] += p;
                    c1 += msk ? 0.f : t;
                    c2 += msk ? 0.f : t * t;
                    Kw[row * 64 + ((jh ^ (row & 7)) * 8) + jlo] = f2bf(p);
                }
            }
            c1 += __shfl_xor(c1, 16); c1 += __shfl_xor(c1, 32);
            c2 += __shfl_xor(c2, 16); c2 += __shfl_xor(c2, 32);
            if (lane < 16 && !msk) {
                const float var = (c2 - c1 * c1 * (1.f / 64.f)) * (1.f / 63.f);
                lossacc += fmaxf(1.f - sqrtf(var + 1e-4f), 0.f);
            }
        }
        // P@V over this wave's 64 keys
#pragma unroll
        for (int ks2 = 0; ks2 < 2; ++ks2) {
            const int grp = (((ks2 * 4 + (lane >> 4)) ^ (frow & 7)) * 8);
            bf16x8_t pa[4], vb[4];
#pragma unroll
            for (int i = 0; i < 4; ++i) {
                pa[i] = *(const bf16x8_t*)(Kw + (i * 16 + frow) * 64 + grp);
                vb[i] = *(const bf16x8_t*)(Vw + (i * 16 + frow) * 64 + grp);
            }
#pragma unroll
            for (int i = 0; i < 4; ++i)
#pragma unroll
                for (int j = 0; j < 4; ++j)
                    oacc[i][j] = __builtin_amdgcn_mfma_f32_16x16x32_bf16(pa[i], vb[j], oacc[i][j], 0, 0, 0);
        }
    }

    // ---------- per-wave Os regions (own dead K/V space), then combine ----------
    float* Osw = (float*)(&wbuf[0][0][0]) + wid * 4096;
#pragma unroll
    for (int i = 0; i < 4; ++i)
#pragma unroll
        for (int j = 0; j < 4; ++j)
#pragma unroll
            for (int r = 0; r < 4; ++r)
                Osw[(i * 16 + cr + r) * 64 + j * 16 + frow] = oacc[i][j][r];

#pragma unroll
    for (int i = 0; i < 16; ++i) {
        float v = rloc[i];
        v += __shfl_xor(v, 1); v += __shfl_xor(v, 2);
        v += __shfl_xor(v, 4); v += __shfl_xor(v, 8);
        rloc[i] = v;
    }
    if ((lane & 15) == 0) {
#pragma unroll
        for (int mt = 0; mt < 4; ++mt)
#pragma unroll
            for (int r = 0; r < 4; ++r)
                RpS[wid][mt * 16 + cr + r] = rloc[mt * 4 + r];
    }
    float v = lossacc;
    v += __shfl_xor(v, 1); v += __shfl_xor(v, 2); v += __shfl_xor(v, 4);
    v += __shfl_xor(v, 8); v += __shfl_xor(v, 16); v += __shfl_xor(v, 32);
    if (lane == 0) lossP[wid] = v;
    __syncthreads();

    const float4* Ob4 = (const float4*)(&wbuf[0][0][0]);
    const size_t ob = (size_t)(bh * 4 + c) * 4096;
#pragma unroll
    for (int p = 0; p < 4; ++p) {
        const int e = tid + p * 256;          // float4 index 0..1023 within a 4096-f tile
        float4 s0 = Ob4[e];
        float4 s1 = Ob4[e + 1024];
        float4 s2 = Ob4[e + 2048];
        float4 s3 = Ob4[e + 3072];
        float4 o;
        o.x = s0.x + s1.x + s2.x + s3.x;
        o.y = s0.y + s1.y + s2.y + s3.y;
        o.z = s0.z + s1.z + s2.z + s3.z;
        o.w = s0.w + s1.w + s2.w + s3.w;
        ((float4*)(Opart + ob))[e] = o;
    }
    if (tid < 64)
        Rpart[(size_t)(bh * 4 + c) * 64 + tid] =
            RpS[0][tid] + RpS[1][tid] + RpS[2][tid] + RpS[3][tid];
    if (tid == 0)
        atomicAdd(loss, (lossP[0] + lossP[1] + lossP[2] + lossP[3]) * (1.f / 524288.f));
}

// ---------------- attention pass 3: combine chunk partials ----------------
__global__ __launch_bounds__(256) void attn_fin(const float* __restrict__ Opart,
                                                const float* __restrict__ Rpart,
                                                u16* __restrict__ ao) {
    const int bh = blockIdx.x, b = bh >> 4, h = bh & 15;
    const int tid = threadIdx.x;
    __shared__ float Rt[64];
    if (tid < 64) {
        float r = 0.f;
#pragma unroll
        for (int cc = 0; cc < 4; ++cc) r += Rpart[(size_t)(bh * 4 + cc) * 64 + tid];
        Rt[tid] = r;
    }
    __syncthreads();
    for (int e = tid; e < 4096; e += 256) {
        float o = 0.f;
#pragma unroll
        for (int cc = 0; cc < 4; ++cc) o += Opart[(size_t)(bh * 4 + cc) * 4096 + e];
        const int row = e >> 6, d = e & 63;
        ao[(size_t)(b * 64 + row) * 1024 + h * 64 + d] = f2bf(o / Rt[row]);
    }
}

// ---------------- host ----------------
extern "C" void kernel_launch(void* const* d_in, const int* in_sizes, int n_in,
                              void* d_out, int out_size, void* d_ws, size_t ws_size,
                              hipStream_t stream) {
    const float* x    = (const float*)d_in[0];
    const float* lat  = (const float*)d_in[1];
    const int*   mask = (const int*)d_in[2];
    const float* Wq   = (const float*)d_in[3];
    const float* Wkv  = (const float*)d_in[4];
    const float* Wout = (const float*)d_in[5];
    float* out = (float*)d_out;

    char* ws = (char*)d_ws;
    u16* x_bf    = (u16*)(ws);                    // 64 MB (reused by partials later)
    u16* kbuf    = (u16*)(ws + 67108864);         // 64 MB: K (32768,1024)
    u16* vtbuf   = (u16*)(ws + 134217728);        // 64 MB: V^T (128 bh,64 d,4096 j)
    u16* wq_bf   = (u16*)(ws + 201326592);
    u16* wkv_bf  = (u16*)(ws + 203423744);
    u16* wout_bf = (u16*)(ws + 207618048);
    u16* lat_bf  = (u16*)(ws + 209715200);
    u16* q_bf    = (u16*)(ws + 210763776);
    u16* ao_bf   = (u16*)(ws + 211812352);
    // attention partials overlay x_bf region (dead after gemm_kv)
    float* Mg    = (float*)(ws);                  // 1024*64*4 = 256 KB
    float* Opart = (float*)(ws + 1048576);        // 8 MB
    float* Rpart = (float*)(ws + 1048576 + 8388608);

    hipMemsetAsync(out + 524288, 0, 4, stream);   // zero loss accumulator

    cvt_all<<<37376, 256, 0, stream>>>(x, lat, Wq, Wkv, Wout,
                                       x_bf, lat_bf, wq_bf, wkv_bf, wout_bf);

    dim3 blk(256);
    gemm_bt64<u16><<<dim3(16, 8), blk, 0, stream>>>(lat_bf, wq_bf, q_bf, 512, 1024, 1024);
    gemm_kv<<<dim3(16, 256), blk, 0, stream>>>(x_bf, wkv_bf, kbuf, vtbuf);
    attn_max<<<1024, blk, 0, stream>>>(q_bf, kbuf, mask, Mg);
    attn_pv<<<512, blk, 0, stream>>>(q_bf, kbuf, vtbuf, mask, Mg, Opart, Rpart, out + 524288);
    attn_fin<<<128, blk, 0, stream>>>(Opart, Rpart, ao_bf);
    gemm_bt64<float><<<dim3(16, 8), blk, 0, stream>>>(ao_bf, wout_bf, out, 512, 1024, 1024);
}